// Round 7
// baseline (7342.895 us; speedup 1.0000x reference)
//
#include <hip/hip_runtime.h>

#define DEV __device__ __forceinline__

constexpr int NN = 50000;
constexpr int NE = 800000;
constexpr int NG = 1024;
constexpr int EMB = 256;
constexpr int NH = 4;
constexpr int HE = 1024;   // NH*EMB
constexpr int NL = 4;
constexpr int TASKS = 128;
constexpr int NS = 50048;            // padded nodes (multiple of 64)
constexpr int NCH = NS / 32;         // 1564 K-chunks for kvs
constexpr int KVS_SL = 64;           // kvs n-slices (TLP for latency hiding)
constexpr int GB64 = NS / 64;        // 782 (covers pad exactly)

using u16 = unsigned short;
using u32 = unsigned int;

typedef __attribute__((ext_vector_type(8))) short short8;
typedef __attribute__((ext_vector_type(4))) float f32x4;

#define MFMA16(a8, b8, c4) __builtin_amdgcn_mfma_f32_16x16x32_bf16(a8, b8, c4, 0, 0, 0)

DEV u16 f2bf(float f) {
  u32 u = __float_as_uint(f);
  u32 r = (u + 0x7FFFu + ((u >> 16) & 1u)) >> 16;
  return (u16)r;
}
DEV float bf2f(u16 s) { return __uint_as_float(((u32)s) << 16); }
DEV short8 ld8(const u16* p) { return *reinterpret_cast<const short8*>(p); }

// ---------------- utility ----------------

__global__ void k_zero(u32* __restrict__ p, int n) {
  int i = blockIdx.x * 256 + threadIdx.x;
  if (i < n) p[i] = 0u;
}

__global__ void k_fill(float* __restrict__ p, int n, float v) {
  int i = blockIdx.x * 256 + threadIdx.x;
  if (i < n) p[i] = v;
}

// transpose-cast: out[b][c][r] (bf16) = in[b][r][c] (f32); R,C multiples of 32
__global__ void k_tcast(const float* __restrict__ in, u16* __restrict__ outp, int R, int C) {
  __shared__ float t[32][33];
  int b = blockIdx.z;
  const float* ip = in + (size_t)b * R * C;
  u16* op = outp + (size_t)b * R * C;
  int r0 = blockIdx.y * 32, c0 = blockIdx.x * 32;
  int tx = threadIdx.x & 31, ty = threadIdx.x >> 5; // 32 x 8
#pragma unroll
  for (int i = 0; i < 4; ++i) t[ty + i * 8][tx] = ip[(size_t)(r0 + ty + i * 8) * C + c0 + tx];
  __syncthreads();
#pragma unroll
  for (int i = 0; i < 4; ++i)
    op[(size_t)(c0 + ty + i * 8) * R + r0 + tx] = f2bf(t[tx][ty + i * 8]);
}

// h transpose: hT[d][n] = h_bf[n][d], zero-padded to NS
__global__ void k_htr(const u16* __restrict__ h_bf, u16* __restrict__ hT) {
  __shared__ u16 t[64][72];
  int tid = threadIdx.x;
  int n0 = blockIdx.x * 64, d0 = blockIdx.y * 64;
#pragma unroll
  for (int rr = 0; rr < 2; ++rr) {
    int nl = rr * 32 + (tid >> 3);
    int dd = (tid & 7) * 8;
    uint4 v = {0u, 0u, 0u, 0u};
    int n = n0 + nl;
    if (n < NN) v = *reinterpret_cast<const uint4*>(h_bf + (size_t)n * EMB + d0 + dd);
    *reinterpret_cast<uint4*>(&t[nl][dd]) = v;
  }
  __syncthreads();
  int dl = tid & 63, q = tid >> 6;
  u32 wbuf[8];
#pragma unroll
  for (int i = 0; i < 8; ++i)
    wbuf[i] = (u32)t[q * 16 + 2 * i][dl] | ((u32)t[q * 16 + 2 * i + 1][dl] << 16);
  uint4 o0 = {wbuf[0], wbuf[1], wbuf[2], wbuf[3]};
  uint4 o1 = {wbuf[4], wbuf[5], wbuf[6], wbuf[7]};
  *reinterpret_cast<uint4*>(hT + (size_t)(d0 + dl) * NS + n0 + q * 16) = o0;
  *reinterpret_cast<uint4*>(hT + (size_t)(d0 + dl) * NS + n0 + q * 16 + 8) = o1;
}

// ---------------- setup kernels ----------------

__global__ void k_atom(const int* __restrict__ x, const float* __restrict__ aemb,
                       u16* __restrict__ h_bf) {
  int n = blockIdx.x, d = threadIdx.x;
  const int* xr = x + n * 9;
  float acc = 0.f;
#pragma unroll
  for (int f = 0; f < 9; ++f) acc += aemb[(f * 100 + xr[f]) * EMB + d];
  h_bf[(size_t)n * EMB + d] = f2bf(acc);
}

__global__ void k_deg(const int* __restrict__ row, const int* __restrict__ col,
                      int* __restrict__ deg_i, int* __restrict__ deg_j) {
  int e = blockIdx.x * 256 + threadIdx.x;
  if (e < NE) {
    atomicAdd(&deg_i[row[e]], 1);
    atomicAdd(&deg_j[col[e]], 1);
  }
}

__global__ void k_dinv(const int* __restrict__ deg_i, const int* __restrict__ deg_j,
                       float* __restrict__ di, float* __restrict__ dj) {
  int n = blockIdx.x * 256 + threadIdx.x;
  if (n < NN) {
    di[n] = deg_i[n] > 0 ? rsqrtf((float)deg_i[n]) : 0.f;
    dj[n] = deg_j[n] > 0 ? rsqrtf((float)deg_j[n]) : 0.f;
  }
}

__global__ void k_scan(const int* __restrict__ deg, int* __restrict__ offs) {
  __shared__ int tot[1024];
  int t = threadIdx.x;
  constexpr int PER = (NN + 1023) / 1024; // 49
  int lo = t * PER, hi = lo + PER;
  if (hi > NN) hi = NN;
  int s = 0;
  for (int i = lo; i < hi; ++i) s += deg[i];
  tot[t] = s;
  __syncthreads();
  for (int off = 1; off < 1024; off <<= 1) {
    int v = (t >= off) ? tot[t - off] : 0;
    __syncthreads();
    tot[t] += v;
    __syncthreads();
  }
  int run = (t == 0) ? 0 : tot[t - 1];
  for (int i = lo; i < hi; ++i) { offs[i] = run; run += deg[i]; }
  if (t == 0) offs[NN] = NE;
}

__global__ void k_csr(const int* __restrict__ row, const int* __restrict__ col,
                      const int* __restrict__ eattr, const float* __restrict__ di,
                      const float* __restrict__ dj, const int* __restrict__ offs,
                      int* __restrict__ cursor, int* __restrict__ csr_col,
                      float* __restrict__ csr_adj, int* __restrict__ csr_pack) {
  int e = blockIdx.x * 256 + threadIdx.x;
  if (e >= NE) return;
  int r = row[e], c = col[e];
  int slot = offs[r] + atomicAdd(&cursor[r], 1);
  csr_col[slot] = c;
  csr_adj[slot] = di[r] * dj[c];
  csr_pack[slot] = eattr[e * 3] | (eattr[e * 3 + 1] << 8) | (eattr[e * 3 + 2] << 16);
}

__global__ void k_gcnt(const int* __restrict__ batch, float* __restrict__ gcnt) {
  int n = blockIdx.x * 256 + threadIdx.x;
  if (n < NN) atomicAdd(&gcnt[batch[n]], 1.f);
}

// ---------------- per-layer kernels ----------------

__global__ void k_message(const float* __restrict__ bond, const int* __restrict__ offs,
                          const float* __restrict__ csr_adj, const int* __restrict__ csr_pack,
                          u16* __restrict__ msg) {
  __shared__ float tab[3 * 10 * EMB]; // 30 KB
  int tid = threadIdx.x;
  for (int i = tid; i < 3 * 10 * EMB; i += 256) tab[i] = bond[i];
  __syncthreads();
  int n0 = blockIdx.x * 16;
  for (int nn = 0; nn < 16; ++nn) {
    int n = n0 + nn;
    int e0 = offs[n], e1 = offs[n + 1];
    float acc = 0.f;
    for (int s = e0; s < e1; ++s) {
      float a = csr_adj[s];
      int pk = csr_pack[s];
      int a0 = pk & 255, a1 = (pk >> 8) & 255, a2 = (pk >> 16) & 255;
      acc += a * (tab[a0 * EMB + tid] + tab[(10 + a1) * EMB + tid] + tab[(20 + a2) * EMB + tid]);
    }
    msg[(size_t)n * EMB + tid] = f2bf(acc);
  }
}

// MFMA k-projection, ONE HEAD per block (low VGPR => high occupancy).
// k = h@Wk + bk, row-normalize, write knT[j][n], accumulate ks_sum (+h_sum on hd 0).
__global__ __launch_bounds__(256) void k_projk(
    const u16* __restrict__ h_bf, const u16* __restrict__ wkT, const float* __restrict__ bk,
    u16* __restrict__ knT, float* __restrict__ ks_sum, float* __restrict__ h_sum) {
  __shared__ __align__(16) u16 aL[32 * 64 * 8]; // 32 KB
  __shared__ float red[4][EMB];                 // 4 KB
  int tid = threadIdx.x;
  int lane = tid & 63, w = tid >> 6;
  int g = lane >> 4, s = lane & 15;
  int n0 = blockIdx.x * 64;
  int hd = blockIdx.y;
  int wrow = w * 16;
  { // stage A tile from h_bf
    int r = tid & 63, kq = tid >> 6;
#pragma unroll
    for (int ii = 0; ii < 8; ++ii) {
      int k = kq * 64 + ii * 8;
      int row = n0 + r;
      uint4 v = {0u, 0u, 0u, 0u};
      if (row < NN) v = *reinterpret_cast<const uint4*>(h_bf + (size_t)row * EMB + k);
      *reinterpret_cast<uint4*>(&aL[((k >> 3) * 64 + r) * 8]) = v;
    }
  }
  __syncthreads();
  if (hd == 0) { // h_sum (column sums over the tile, from bf16) — once per tile
    float ss = 0.f;
#pragma unroll 8
    for (int r = 0; r < 64; ++r) ss += bf2f(aL[((tid >> 3) * 64 + r) * 8 + (tid & 7)]);
    atomicAdd(&h_sum[tid], ss);
  }
  f32x4 ka[16] = {};
#pragma unroll
  for (int k0 = 0; k0 < 256; k0 += 32) {
    short8 a = ld8(&aL[(((k0 >> 3) + g) * 64 + wrow + s) * 8]);
#pragma unroll
    for (int c = 0; c < 16; ++c) {
      short8 b = ld8(wkT + (size_t)(hd * 256 + c * 16 + s) * 256 + k0 + g * 8);
      ka[c] = MFMA16(a, b, ka[c]);
    }
  }
  float nr[4] = {0.f, 0.f, 0.f, 0.f};
#pragma unroll
  for (int c = 0; c < 16; ++c) {
    float bv = bk[hd * 256 + c * 16 + s];
#pragma unroll
    for (int r = 0; r < 4; ++r) {
      ka[c][r] += bv;
      nr[r] += ka[c][r] * ka[c][r];
    }
  }
#pragma unroll
  for (int r = 0; r < 4; ++r) {
    nr[r] += __shfl_xor(nr[r], 1, 64);
    nr[r] += __shfl_xor(nr[r], 2, 64);
    nr[r] += __shfl_xor(nr[r], 4, 64);
    nr[r] += __shfl_xor(nr[r], 8, 64);
  }
  float rn[4];
#pragma unroll
  for (int r = 0; r < 4; ++r) {
    int row = n0 + wrow + g * 4 + r;
    rn[r] = (row < NN && nr[r] > 0.f) ? rsqrtf(nr[r]) : 0.f; // 0 for pad rows
  }
  float cs[16];
#pragma unroll
  for (int c = 0; c < 16; ++c) {
    float v0 = ka[c][0] * rn[0], v1 = ka[c][1] * rn[1];
    float v2 = ka[c][2] * rn[2], v3 = ka[c][3] * rn[3];
    cs[c] = v0 + v1 + v2 + v3;
    ushort4 pk;
    pk.x = f2bf(v0); pk.y = f2bf(v1); pk.z = f2bf(v2); pk.w = f2bf(v3);
    *reinterpret_cast<ushort4*>(knT + (size_t)(hd * 256 + c * 16 + s) * NS + n0 + wrow + g * 4) = pk;
  }
#pragma unroll
  for (int c = 0; c < 16; ++c) {
    cs[c] += __shfl_xor(cs[c], 16, 64);
    cs[c] += __shfl_xor(cs[c], 32, 64);
  }
  if (g == 0) {
#pragma unroll
    for (int c = 0; c < 16; ++c) red[w][c * 16 + s] = cs[c];
  }
  __syncthreads();
  float tot = red[0][tid] + red[1][tid] + red[2][tid] + red[3][tid];
  atomicAdd(&ks_sum[hd * 256 + tid], tot);
}

// MFMA kvs: kvs[j][d] += sum_n knT[j][n] * hT[d][n]; direct global fragments.
__global__ __launch_bounds__(256) void k_kvs(const u16* __restrict__ knT,
                                             const u16* __restrict__ hT,
                                             float* __restrict__ kvs) {
  int tid = threadIdx.x;
  int lane = tid & 63, w = tid >> 6;
  int s = lane & 15, g = lane >> 4;
  int j0 = blockIdx.x * 64;
  int sl = blockIdx.y;
  f32x4 acc[4][4] = {}; // [jf][df]
  const u16* ap = knT + (size_t)(j0 + s) * NS + g * 8;
  const u16* bp = hT + (size_t)(w * 64 + s) * NS + g * 8;
  for (int ch = sl; ch < NCH; ch += KVS_SL) {
    int n0 = ch * 32;
    short8 bfr[4];
#pragma unroll
    for (int df = 0; df < 4; ++df) bfr[df] = ld8(bp + (size_t)df * 16 * NS + n0);
#pragma unroll
    for (int jf = 0; jf < 4; ++jf) {
      short8 a = ld8(ap + (size_t)jf * 16 * NS + n0);
#pragma unroll
      for (int df = 0; df < 4; ++df) acc[jf][df] = MFMA16(a, bfr[df], acc[jf][df]);
    }
  }
#pragma unroll
  for (int jf = 0; jf < 4; ++jf)
#pragma unroll
    for (int df = 0; df < 4; ++df)
#pragma unroll
      for (int r = 0; r < 4; ++r)
        atomicAdd(&kvs[(size_t)(j0 + jf * 16 + g * 4 + r) * EMB + w * 64 + df * 16 + s],
                  acc[jf][df][r]);
}

// M[hd*256+m][o] = sum_d kvs[hd*256+m][d] * fcw[(hd*256+d)*256+o]  (fp32)
__global__ void k_mpre(const float* __restrict__ kvs, const float* __restrict__ fcw,
                       float* __restrict__ M) {
  __shared__ float arow[EMB];
  int bid = blockIdx.x; // hd*256+m
  int hd = bid >> 8;
  int t = threadIdx.x;
  arow[t] = kvs[(size_t)bid * EMB + t];
  __syncthreads();
  float acc = 0.f;
  const float* wp = fcw + (size_t)(hd * 256) * EMB + t;
#pragma unroll 4
  for (int d = 0; d < EMB; ++d) acc += arow[d] * wp[(size_t)d * EMB];
  M[(size_t)bid * EMB + t] = acc;
}

__global__ void k_cvec(const float* __restrict__ h_sum, const float* __restrict__ fcw,
                       float* __restrict__ c) {
  __shared__ float arow[EMB];
  int hd = blockIdx.x;
  int t = threadIdx.x;
  arow[t] = h_sum[t];
  __syncthreads();
  float acc = 0.f;
  const float* wp = fcw + (size_t)(hd * 256) * EMB + t;
#pragma unroll 4
  for (int d = 0; d < EMB; ++d) acc += arow[d] * wp[(size_t)d * EMB];
  c[hd * EMB + t] = acc;
}

// SpMM: wave-per-node, lane owns 4 cols; bf16 in/out, 4-edge unroll.
__global__ __launch_bounds__(256) void k_spmm(
    const u16* __restrict__ xin, const u16* __restrict__ msg,
    const int* __restrict__ offs, const int* __restrict__ csr_col,
    const float* __restrict__ csr_adj, u16* __restrict__ sout) {
  int lane = threadIdx.x & 63, w = threadIdx.x >> 6;
  int n = blockIdx.x * 4 + w;
  if (n >= NN) return;
  int c4 = lane * 4;
  uint2 m = *reinterpret_cast<const uint2*>(msg + (size_t)n * EMB + c4);
  float a0 = bf2f(m.x & 0xffff), a1 = bf2f(m.x >> 16);
  float a2 = bf2f(m.y & 0xffff), a3 = bf2f(m.y >> 16);
  int e0 = offs[n], e1 = offs[n + 1];
  int s = e0;
  for (; s + 4 <= e1; s += 4) {
    int col0 = csr_col[s], col1 = csr_col[s + 1], col2 = csr_col[s + 2], col3 = csr_col[s + 3];
    float w0 = csr_adj[s], w1 = csr_adj[s + 1], w2 = csr_adj[s + 2], w3 = csr_adj[s + 3];
    uint2 r0 = *reinterpret_cast<const uint2*>(xin + (size_t)col0 * EMB + c4);
    uint2 r1 = *reinterpret_cast<const uint2*>(xin + (size_t)col1 * EMB + c4);
    uint2 r2 = *reinterpret_cast<const uint2*>(xin + (size_t)col2 * EMB + c4);
    uint2 r3 = *reinterpret_cast<const uint2*>(xin + (size_t)col3 * EMB + c4);
    a0 += w0 * bf2f(r0.x & 0xffff) + w1 * bf2f(r1.x & 0xffff) + w2 * bf2f(r2.x & 0xffff) + w3 * bf2f(r3.x & 0xffff);
    a1 += w0 * bf2f(r0.x >> 16)    + w1 * bf2f(r1.x >> 16)    + w2 * bf2f(r2.x >> 16)    + w3 * bf2f(r3.x >> 16);
    a2 += w0 * bf2f(r0.y & 0xffff) + w1 * bf2f(r1.y & 0xffff) + w2 * bf2f(r2.y & 0xffff) + w3 * bf2f(r3.y & 0xffff);
    a3 += w0 * bf2f(r0.y >> 16)    + w1 * bf2f(r1.y >> 16)    + w2 * bf2f(r2.y >> 16)    + w3 * bf2f(r3.y >> 16);
  }
  for (; s < e1; ++s) {
    int col = csr_col[s];
    float wv = csr_adj[s];
    uint2 r0 = *reinterpret_cast<const uint2*>(xin + (size_t)col * EMB + c4);
    a0 += wv * bf2f(r0.x & 0xffff);
    a1 += wv * bf2f(r0.x >> 16);
    a2 += wv * bf2f(r0.y & 0xffff);
    a3 += wv * bf2f(r0.y >> 16);
  }
  ushort4 o;
  o.x = f2bf(a0); o.y = f2bf(a1); o.z = f2bf(a2); o.w = f2bf(a3);
  *reinterpret_cast<ushort4*>(sout + (size_t)n * EMB + c4) = o;
}

// Attention, ONE HEAD per block: q-proj -> norm/denom -> pack q*(rn*rdv) to
// bf16 regs (frees qa) -> PV via qL halves -> atomicAdd into z_attn (f32).
__global__ __launch_bounds__(256) void k_attnh(
    const u16* __restrict__ h_bf,
    const u16* __restrict__ wqT, const float* __restrict__ bq,
    const u16* __restrict__ MT, const float* __restrict__ cvec, const float* __restrict__ kss,
    float* __restrict__ z_attn) {
  __shared__ __align__(16) u16 aL[32 * 64 * 8]; // 32 KB
  __shared__ __align__(16) u16 qL[16 * 64 * 8]; // 16 KB (one m-half)
  int tid = threadIdx.x;
  int lane = tid & 63, w = tid >> 6;
  int g = lane >> 4, s = lane & 15;
  int n0 = blockIdx.x * 64;
  int hd = blockIdx.y;
  int wrow = w * 16;
  { // stage h tile
    int r = tid & 63, kq = tid >> 6;
#pragma unroll
    for (int ii = 0; ii < 8; ++ii) {
      int k = kq * 64 + ii * 8;
      int row = n0 + r;
      uint4 v = {0u, 0u, 0u, 0u};
      if (row < NN) v = *reinterpret_cast<const uint4*>(h_bf + (size_t)row * EMB + k);
      *reinterpret_cast<uint4*>(&aL[((k >> 3) * 64 + r) * 8]) = v;
    }
  }
  __syncthreads();

  // ---- q-proj ----
  float rdv[4];
  u32 qbf[16][2]; // q*(rn*rdv) packed bf16 pairs (r0r1, r2r3)
  {
    f32x4 qa[16] = {};
#pragma unroll
    for (int k0 = 0; k0 < 256; k0 += 32) {
      short8 a = ld8(&aL[(((k0 >> 3) + g) * 64 + wrow + s) * 8]);
#pragma unroll
      for (int c = 0; c < 16; ++c) {
        short8 b = ld8(wqT + (size_t)(hd * 256 + c * 16 + s) * 256 + k0 + g * 8);
        qa[c] = MFMA16(a, b, qa[c]);
      }
    }
    float nr[4] = {0.f, 0.f, 0.f, 0.f};
    float dp[4] = {0.f, 0.f, 0.f, 0.f};
#pragma unroll
    for (int c = 0; c < 16; ++c) {
      float bv = bq[hd * 256 + c * 16 + s];
      float kv = kss[hd * 256 + c * 16 + s];
#pragma unroll
      for (int r = 0; r < 4; ++r) {
        qa[c][r] += bv;
        nr[r] += qa[c][r] * qa[c][r];
        dp[r] += qa[c][r] * kv;
      }
    }
#pragma unroll
    for (int r = 0; r < 4; ++r) {
      nr[r] += __shfl_xor(nr[r], 1, 64);
      nr[r] += __shfl_xor(nr[r], 2, 64);
      nr[r] += __shfl_xor(nr[r], 4, 64);
      nr[r] += __shfl_xor(nr[r], 8, 64);
      dp[r] += __shfl_xor(dp[r], 1, 64);
      dp[r] += __shfl_xor(dp[r], 2, 64);
      dp[r] += __shfl_xor(dp[r], 4, 64);
      dp[r] += __shfl_xor(dp[r], 8, 64);
    }
    float sc[4];
#pragma unroll
    for (int r = 0; r < 4; ++r) {
      int row = n0 + wrow + g * 4 + r;
      float rn = (row < NN && nr[r] > 0.f) ? rsqrtf(nr[r]) : 0.f;
      rdv[r] = 1.f / (dp[r] * rn + (float)NN);
      sc[r] = rn * rdv[r]; // fold normalize AND 1/denom into the q fragment
    }
#pragma unroll
    for (int c = 0; c < 16; ++c) {
      qbf[c][0] = (u32)f2bf(qa[c][0] * sc[0]) | ((u32)f2bf(qa[c][1] * sc[1]) << 16);
      qbf[c][1] = (u32)f2bf(qa[c][2] * sc[2]) | ((u32)f2bf(qa[c][3] * sc[3]) << 16);
    }
  } // qa dead here — frees 64 VGPRs before PV

  // ---- PV in two m-halves ----
  f32x4 pv[16] = {};
#pragma unroll
  for (int hh = 0; hh < 2; ++hh) {
    __syncthreads(); // qL free (prev half read done)
#pragma unroll
    for (int c = hh * 8; c < hh * 8 + 8; ++c) {
      int mh = (c - hh * 8) * 16 + s;
#pragma unroll
      for (int r = 0; r < 4; ++r) {
        u16 qv = (u16)(qbf[c][r >> 1] >> ((r & 1) * 16));
        qL[((mh >> 3) * 64 + wrow + g * 4 + r) * 8 + (mh & 7)] = qv;
      }
    }
    __syncthreads();
#pragma unroll
    for (int k0 = 0; k0 < 128; k0 += 32) {
      short8 a = ld8(&qL[(((k0 >> 3) + g) * 64 + wrow + s) * 8]);
#pragma unroll
      for (int c = 0; c < 16; ++c) {
        short8 b = ld8(MT + (size_t)(hd * 256 + c * 16 + s) * 256 + hh * 128 + k0 + g * 8);
        pv[c] = MFMA16(a, b, pv[c]);
      }
    }
  }

  // ---- emit: z_attn += pv + cvec*rdv ----
#pragma unroll
  for (int c = 0; c < 16; ++c) {
    int col = c * 16 + s;
    float cv = cvec[hd * 256 + col];
#pragma unroll
    for (int r = 0; r < 4; ++r) {
      int row = n0 + wrow + g * 4 + r;
      if (row < NN) atomicAdd(&z_attn[(size_t)row * EMB + col], pv[c][r] + cv * rdv[r]);
    }
  }
}

// FC tail: zac = residual(h) + [h|s1|s2|s3]@fcw[1024:] ; + z_attn + fc_b; LN; relu.
__global__ __launch_bounds__(256) void k_fc(
    u16* __restrict__ h_bf,
    const u16* __restrict__ s1, const u16* __restrict__ s2, const u16* __restrict__ s3,
    const float* __restrict__ z_attn,
    const u16* __restrict__ fcwT, const float* __restrict__ fcb,
    const float* __restrict__ lg, const float* __restrict__ lb) {
  __shared__ __align__(16) u16 aL[32 * 64 * 8]; // 32 KB only
  int tid = threadIdx.x;
  int lane = tid & 63, w = tid >> 6;
  int g = lane >> 4, s = lane & 15;
  int n0 = blockIdx.x * 64;
  int wrow = w * 16;
  f32x4 zac[16];
  for (int sg = 0; sg < 4; ++sg) {
    const u16* sp = (sg == 0) ? h_bf : (sg == 1) ? s1 : (sg == 2) ? s2 : s3;
    if (sg > 0) __syncthreads();
    {
      int r = tid & 63, kq = tid >> 6;
#pragma unroll
      for (int ii = 0; ii < 8; ++ii) {
        int k = kq * 64 + ii * 8;
        int row = n0 + r;
        uint4 v = {0u, 0u, 0u, 0u};
        if (row < NN) v = *reinterpret_cast<const uint4*>(sp + (size_t)row * EMB + k);
        *reinterpret_cast<uint4*>(&aL[((k >> 3) * 64 + r) * 8]) = v;
      }
    }
    __syncthreads();
    if (sg == 0) { // residual init from staged h
#pragma unroll
      for (int c = 0; c < 16; ++c) {
        int col = c * 16 + s;
#pragma unroll
        for (int r = 0; r < 4; ++r)
          zac[c][r] = bf2f(aL[((col >> 3) * 64 + wrow + g * 4 + r) * 8 + (col & 7)]);
      }
    }
#pragma unroll
    for (int k0 = 0; k0 < 256; k0 += 32) {
      short8 a = ld8(&aL[(((k0 >> 3) + g) * 64 + wrow + s) * 8]);
#pragma unroll
      for (int c = 0; c < 16; ++c) {
        short8 b = ld8(fcwT + (size_t)(c * 16 + s) * 2048 + 1024 + sg * 256 + k0 + g * 8);
        zac[c] = MFMA16(a, b, zac[c]);
      }
    }
  }

  // ---- epilogue: + z_attn + fc_b, LN, relu, store h_bf ----
  float sm[4] = {0.f, 0.f, 0.f, 0.f}, sq[4] = {0.f, 0.f, 0.f, 0.f};
#pragma unroll
  for (int c = 0; c < 16; ++c) {
    int col = c * 16 + s;
    float fb = fcb[col];
#pragma unroll
    for (int r = 0; r < 4; ++r) {
      int row = n0 + wrow + g * 4 + r;
      float za = (row < NN) ? z_attn[(size_t)row * EMB + col] : 0.f;
      float v = zac[c][r] + fb + za;
      zac[c][r] = v;
      sm[r] += v;
      sq[r] += v * v;
    }
  }
#pragma unroll
  for (int r = 0; r < 4; ++r) {
    sm[r] += __shfl_xor(sm[r], 1, 64);
    sm[r] += __shfl_xor(sm[r], 2, 64);
    sm[r] += __shfl_xor(sm[r], 4, 64);
    sm[r] += __shfl_xor(sm[r], 8, 64);
    sq[r] += __shfl_xor(sq[r], 1, 64);
    sq[r] += __shfl_xor(sq[r], 2, 64);
    sq[r] += __shfl_xor(sq[r], 4, 64);
    sq[r] += __shfl_xor(sq[r], 8, 64);
  }
  float mu[4], rs[4];
#pragma unroll
  for (int r = 0; r < 4; ++r) {
    mu[r] = sm[r] * (1.f / 256.f);
    float var = sq[r] * (1.f / 256.f) - mu[r] * mu[r];
    rs[r] = rsqrtf(var + 1e-5f);
  }
#pragma unroll
  for (int c = 0; c < 16; ++c) {
    int col = c * 16 + s;
    float gg = lg[col], bb = lb[col];
#pragma unroll
    for (int r = 0; r < 4; ++r) {
      int row = n0 + wrow + g * 4 + r;
      if (row < NN) {
        float o = fmaxf(0.f, (zac[c][r] - mu[r]) * rs[r] * gg + bb);
        h_bf[(size_t)row * EMB + col] = f2bf(o);
      }
    }
  }
}

// ---------------- pooling / output ----------------

// segmented pool: batch is sorted, flush on graph change
__global__ void k_pool(const u16* __restrict__ h_bf, const int* __restrict__ batch,
                       float* __restrict__ pooled) {
  int t = threadIdx.x; // col
  int n0 = blockIdx.x * 64;
  if (n0 >= NN) return;
  int nend = n0 + 64;
  if (nend > NN) nend = NN;
  float run = 0.f;
  int cur = batch[n0];
  for (int n = n0; n < nend; ++n) {
    int b = batch[n];
    if (b != cur) {
      atomicAdd(&pooled[(size_t)cur * EMB + t], run);
      run = 0.f;
      cur = b;
    }
    run += bf2f(h_bf[(size_t)n * EMB + t]);
  }
  atomicAdd(&pooled[(size_t)cur * EMB + t], run);
}

__global__ void k_out(const float* __restrict__ pooled, const float* __restrict__ gcnt,
                      const float* __restrict__ ow, const float* __restrict__ ob,
                      float* __restrict__ out) {
  __shared__ float prow[EMB];
  int g = blockIdx.x, t = threadIdx.x;
  float rc = 1.f / fmaxf(gcnt[g], 1.f);
  for (int i = t; i < EMB; i += TASKS) prow[i] = pooled[(size_t)g * EMB + i] * rc;
  __syncthreads();
  float acc = ob[t];
#pragma unroll 4
  for (int d = 0; d < EMB; ++d) acc += prow[d] * ow[d * TASKS + t];
  out[(size_t)g * TASKS + t] = acc;
}

// ---------------- launch ----------------

extern "C" void kernel_launch(void* const* d_in, const int* in_sizes, int n_in,
                              void* d_out, int out_size, void* d_ws, size_t ws_size,
                              hipStream_t stream) {
  const int* x = (const int*)d_in[0];
  const int* eidx = (const int*)d_in[1];
  const int* eattr = (const int*)d_in[2];
  const int* batch = (const int*)d_in[3];
  const float* aemb = (const float*)d_in[4];
  const float* bemb = (const float*)d_in[5];
  const float* wq = (const float*)d_in[6];
  const float* bq = (const float*)d_in[7];
  const float* wk = (const float*)d_in[8];
  const float* bk = (const float*)d_in[9];
  const float* fcw = (const float*)d_in[10];
  const float* fcb = (const float*)d_in[11];
  const float* lg = (const float*)d_in[12];
  const float* lb = (const float*)d_in[13];
  const float* ow = (const float*)d_in[14];
  const float* ob = (const float*)d_in[15];
  float* out = (float*)d_out;

  size_t off = 0;
  auto alloc = [&](size_t bytes) -> void* {
    void* r = (char*)d_ws + off;
    off += (bytes + 255) & ~(size_t)255;
    return r;
  };
  u16* h_bf = (u16*)alloc((size_t)NN * EMB * 2);        // 25.6 MB
  u16* region = (u16*)alloc((size_t)HE * NS * 2);       // 102.5 MB (knT | msg,s1,s2,s3)
  u16* knT = region;
  u16* msg = region;
  u16* s1 = region + (size_t)NN * EMB;
  u16* s2 = region + (size_t)2 * NN * EMB;
  u16* s3 = region + (size_t)3 * NN * EMB;
  u16* hT = (u16*)alloc((size_t)EMB * NS * 2);          // 25.6 MB
  float* z_attn = (float*)alloc((size_t)NN * EMB * 4);  // 51.2 MB
  float* kvs = (float*)alloc((size_t)HE * EMB * 4);     // 1 MB
  float* Mm = (float*)alloc((size_t)HE * EMB * 4);      // 1 MB
  u16* MT = (u16*)alloc((size_t)HE * EMB * 2);          // 0.5 MB
  u16* wqT = (u16*)alloc((size_t)NL * HE * EMB * 2);    // 2.1 MB
  u16* wkT = (u16*)alloc((size_t)NL * HE * EMB * 2);    // 2.1 MB
  u16* fcwT = (u16*)alloc((size_t)NL * 2048 * EMB * 2); // 4.2 MB
  float* cvec = (float*)alloc((size_t)NH * EMB * 4);
  float* ksh = (float*)alloc((size_t)(HE + EMB) * 4); // ks_sum | h_sum
  float* ks_sum = ksh;
  float* h_sum = ksh + HE;
  float* dinv_i = (float*)alloc((size_t)NN * 4);
  float* dinv_j = (float*)alloc((size_t)NN * 4);
  int* deg_i = (int*)alloc((size_t)NN * 4);
  int* deg_j = (int*)alloc((size_t)NN * 4);
  int* offs = (int*)alloc((size_t)(NN + 1) * 4);
  int* cursor = (int*)alloc((size_t)NN * 4);
  int* csr_col = (int*)alloc((size_t)NE * 4);
  float* csr_adj = (float*)alloc((size_t)NE * 4);
  int* csr_pack = (int*)alloc((size_t)NE * 4);
  float* pooled = (float*)alloc((size_t)NG * EMB * 4);
  float* gcnt = (float*)alloc((size_t)NG * 4);

  if (off > ws_size) {
    k_fill<<<(out_size + 255) / 256, 256, 0, stream>>>(out, out_size, 1048576.f);
    return;
  }

  const int* row = eidx;
  const int* colp = eidx + NE;

  k_zero<<<(NN + 255) / 256, 256, 0, stream>>>((u32*)deg_i, NN);
  k_zero<<<(NN + 255) / 256, 256, 0, stream>>>((u32*)deg_j, NN);
  k_zero<<<(NN + 255) / 256, 256, 0, stream>>>((u32*)cursor, NN);
  k_zero<<<(NG + 255) / 256, 256, 0, stream>>>((u32*)gcnt, NG);
  k_zero<<<(NG * EMB + 255) / 256, 256, 0, stream>>>((u32*)pooled, NG * EMB);

  // one-time weight transpose-casts
  k_tcast<<<dim3(32, 8, NL), 256, 0, stream>>>(wq, wqT, 256, 1024);
  k_tcast<<<dim3(32, 8, NL), 256, 0, stream>>>(wk, wkT, 256, 1024);
  k_tcast<<<dim3(8, 64, NL), 256, 0, stream>>>(fcw, fcwT, 2048, 256);

  k_atom<<<NN, EMB, 0, stream>>>(x, aemb, h_bf);
  k_deg<<<NE / 256, 256, 0, stream>>>(row, colp, deg_i, deg_j);
  k_dinv<<<(NN + 255) / 256, 256, 0, stream>>>(deg_i, deg_j, dinv_i, dinv_j);
  k_scan<<<1, 1024, 0, stream>>>(deg_i, offs);
  k_csr<<<NE / 256, 256, 0, stream>>>(row, colp, eattr, dinv_i, dinv_j, offs, cursor,
                                      csr_col, csr_adj, csr_pack);
  k_gcnt<<<(NN + 255) / 256, 256, 0, stream>>>(batch, gcnt);

  for (int l = 0; l < NL; ++l) {
    const float* fcw_l = fcw + (size_t)l * 2048 * EMB;
    k_zero<<<(HE + EMB + 255) / 256, 256, 0, stream>>>((u32*)ksh, HE + EMB);
    k_zero<<<(HE * EMB + 255) / 256, 256, 0, stream>>>((u32*)kvs, HE * EMB);
    k_zero<<<(NN * EMB + 255) / 256, 256, 0, stream>>>((u32*)z_attn, NN * EMB);
    // --- phase 1: region holds knT ---
    k_projk<<<dim3(GB64, NH), 256, 0, stream>>>(h_bf, wkT + (size_t)l * HE * EMB,
                                                bk + (size_t)l * HE, knT, ks_sum, h_sum);
    k_htr<<<dim3(GB64, 4), 256, 0, stream>>>(h_bf, hT);
    k_kvs<<<dim3(16, KVS_SL), 256, 0, stream>>>(knT, hT, kvs);
    k_mpre<<<HE, 256, 0, stream>>>(kvs, fcw_l, Mm);
    k_tcast<<<dim3(8, 8, NH), 256, 0, stream>>>(Mm, MT, 256, 256);
    k_cvec<<<NH, 256, 0, stream>>>(h_sum, fcw_l, cvec);
    k_attnh<<<dim3(GB64, NH), 256, 0, stream>>>(h_bf, wqT + (size_t)l * HE * EMB,
                                                bq + (size_t)l * HE, MT, cvec, ks_sum, z_attn);
    // --- phase 2: knT dead; region becomes msg/s1/s2/s3 ---
    k_message<<<NN / 16, 256, 0, stream>>>(bemb + (size_t)l * 3 * 10 * EMB, offs, csr_adj,
                                           csr_pack, msg);
    k_spmm<<<NN / 4, 256, 0, stream>>>(h_bf, msg, offs, csr_col, csr_adj, s1);
    k_spmm<<<NN / 4, 256, 0, stream>>>(s1, msg, offs, csr_col, csr_adj, s2);
    k_spmm<<<NN / 4, 256, 0, stream>>>(s2, msg, offs, csr_col, csr_adj, s3);
    k_fc<<<GB64, 256, 0, stream>>>(h_bf, s1, s2, s3, z_attn,
                                   fcwT + (size_t)l * 2048 * EMB, fcb + (size_t)l * EMB,
                                   lg + (size_t)l * EMB, lb + (size_t)l * EMB);
  }
  k_pool<<<(NN + 63) / 64, 256, 0, stream>>>(h_bf, batch, pooled);
  k_out<<<NG, TASKS, 0, stream>>>(pooled, gcnt, ow, ob, out);
}

// Round 8
// 4455.886 us; speedup vs baseline: 1.6479x; 1.6479x over previous
//
#include <hip/hip_runtime.h>

#define DEV __device__ __forceinline__

constexpr int NN = 50000;
constexpr int NE = 800000;
constexpr int NG = 1024;
constexpr int EMB = 256;
constexpr int NH = 4;
constexpr int HE = 1024;   // NH*EMB
constexpr int NL = 4;
constexpr int TASKS = 128;
constexpr int NS = 50048;            // padded nodes (multiple of 64)
constexpr int NCH = NS / 32;         // 1564 K-chunks for kvs
constexpr int KVS_SL = 64;           // kvs n-slices (TLP)
constexpr int GB64 = NS / 64;        // 782

using u16 = unsigned short;
using u32 = unsigned int;

typedef __attribute__((ext_vector_type(8))) short short8;
typedef __attribute__((ext_vector_type(4))) float f32x4;

#define MFMA16(a8, b8, c4) __builtin_amdgcn_mfma_f32_16x16x32_bf16(a8, b8, c4, 0, 0, 0)

DEV u16 f2bf(float f) {
  u32 u = __float_as_uint(f);
  u32 r = (u + 0x7FFFu + ((u >> 16) & 1u)) >> 16;
  return (u16)r;
}
DEV float bf2f(u16 s) { return __uint_as_float(((u32)s) << 16); }
DEV short8 ld8(const u16* p) { return *reinterpret_cast<const short8*>(p); }

// ---------------- utility ----------------

__global__ void k_zero(u32* __restrict__ p, int n) {
  int i = blockIdx.x * 256 + threadIdx.x;
  if (i < n) p[i] = 0u;
}

__global__ void k_fill(float* __restrict__ p, int n, float v) {
  int i = blockIdx.x * 256 + threadIdx.x;
  if (i < n) p[i] = v;
}

// Pack a [K][R] f32 matrix (row n = K-dim, col r = output-row dim) into
// MFMA B-fragment-major bf16: one ld8 per (fragment, lane) is 1KB contiguous
// per wave.  F[((nc*rqTot + b*rqStep + rq)*64 + lane)*8 + j]
//   = in[b*inStride + (nc*32 + g*8 + j)*R + rq*16 + s],  lane = g*16+s.
__global__ void k_frag(const float* __restrict__ in, u16* __restrict__ outp,
                       int R, int rqTot, int rqStep, long inStride, long outStride) {
  int nc = blockIdx.x, rq = blockIdx.y, b = blockIdx.z;
  int l = threadIdx.x & 63;
  int g = l >> 4, s = l & 15;
  const float* ip = in + (size_t)b * inStride + (size_t)(nc * 32 + g * 8) * R + rq * 16 + s;
  short8 v;
#pragma unroll
  for (int j = 0; j < 8; ++j) v[j] = (short)f2bf(ip[(size_t)j * R]);
  u16* op = outp + (size_t)b * outStride +
            ((size_t)(nc * rqTot + b * rqStep + rq) * 64 + l) * 8;
  *reinterpret_cast<short8*>(op) = v;
}

// h -> fragment-major hF (K = node dim, rows = d).  Zero-padded to NS.
__global__ void k_htrf(const u16* __restrict__ h_bf, u16* __restrict__ hF) {
  __shared__ u16 t[64][72];
  int tid = threadIdx.x;
  int n0 = blockIdx.x * 64, d0 = blockIdx.y * 64;
#pragma unroll
  for (int rr = 0; rr < 2; ++rr) {
    int nl = rr * 32 + (tid >> 3);
    int dd = (tid & 7) * 8;
    uint4 v = {0u, 0u, 0u, 0u};
    int n = n0 + nl;
    if (n < NN) v = *reinterpret_cast<const uint4*>(h_bf + (size_t)n * EMB + d0 + dd);
    *reinterpret_cast<uint4*>(&t[nl][dd]) = v;
  }
  __syncthreads();
#pragma unroll
  for (int k = 0; k < 2; ++k) {
    int u = tid + 256 * k;          // 512 output ushort8 units
    int nchL = u >> 8;              // 0..1
    int rqL = (u >> 6) & 3;         // 0..3
    int l = u & 63;
    int g = l >> 4, s = l & 15;
    short8 v;
#pragma unroll
    for (int j = 0; j < 8; ++j) v[j] = (short)t[nchL * 32 + g * 8 + j][rqL * 16 + s];
    *reinterpret_cast<short8*>(
        &hF[(((size_t)((n0 >> 5) + nchL) * 16 + (d0 >> 4) + rqL) * 64 + l) * 8]) = v;
  }
}

// ---------------- setup kernels ----------------

__global__ void k_atom(const int* __restrict__ x, const float* __restrict__ aemb,
                       u16* __restrict__ h_bf) {
  int n = blockIdx.x, d = threadIdx.x;
  const int* xr = x + n * 9;
  float acc = 0.f;
#pragma unroll
  for (int f = 0; f < 9; ++f) acc += aemb[(f * 100 + xr[f]) * EMB + d];
  h_bf[(size_t)n * EMB + d] = f2bf(acc);
}

__global__ void k_deg(const int* __restrict__ row, const int* __restrict__ col,
                      int* __restrict__ deg_i, int* __restrict__ deg_j) {
  int e = blockIdx.x * 256 + threadIdx.x;
  if (e < NE) {
    atomicAdd(&deg_i[row[e]], 1);
    atomicAdd(&deg_j[col[e]], 1);
  }
}

__global__ void k_dinv(const int* __restrict__ deg_i, const int* __restrict__ deg_j,
                       float* __restrict__ di, float* __restrict__ dj) {
  int n = blockIdx.x * 256 + threadIdx.x;
  if (n < NN) {
    di[n] = deg_i[n] > 0 ? rsqrtf((float)deg_i[n]) : 0.f;
    dj[n] = deg_j[n] > 0 ? rsqrtf((float)deg_j[n]) : 0.f;
  }
}

__global__ void k_scan(const int* __restrict__ deg, int* __restrict__ offs) {
  __shared__ int tot[1024];
  int t = threadIdx.x;
  constexpr int PER = (NN + 1023) / 1024; // 49
  int lo = t * PER, hi = lo + PER;
  if (hi > NN) hi = NN;
  int s = 0;
  for (int i = lo; i < hi; ++i) s += deg[i];
  tot[t] = s;
  __syncthreads();
  for (int off = 1; off < 1024; off <<= 1) {
    int v = (t >= off) ? tot[t - off] : 0;
    __syncthreads();
    tot[t] += v;
    __syncthreads();
  }
  int run = (t == 0) ? 0 : tot[t - 1];
  for (int i = lo; i < hi; ++i) { offs[i] = run; run += deg[i]; }
  if (t == 0) offs[NN] = NE;
}

__global__ void k_csr(const int* __restrict__ row, const int* __restrict__ col,
                      const int* __restrict__ eattr, const float* __restrict__ di,
                      const float* __restrict__ dj, const int* __restrict__ offs,
                      int* __restrict__ cursor, int* __restrict__ csr_col,
                      float* __restrict__ csr_adj, int* __restrict__ csr_pack) {
  int e = blockIdx.x * 256 + threadIdx.x;
  if (e >= NE) return;
  int r = row[e], c = col[e];
  int slot = offs[r] + atomicAdd(&cursor[r], 1);
  csr_col[slot] = c;
  csr_adj[slot] = di[r] * dj[c];
  csr_pack[slot] = eattr[e * 3] | (eattr[e * 3 + 1] << 8) | (eattr[e * 3 + 2] << 16);
}

__global__ void k_gcnt(const int* __restrict__ batch, float* __restrict__ gcnt) {
  int n = blockIdx.x * 256 + threadIdx.x;
  if (n < NN) atomicAdd(&gcnt[batch[n]], 1.f);
}

// ---------------- per-layer kernels ----------------

__global__ void k_message(const float* __restrict__ bond, const int* __restrict__ offs,
                          const float* __restrict__ csr_adj, const int* __restrict__ csr_pack,
                          u16* __restrict__ msg) {
  __shared__ float tab[3 * 10 * EMB]; // 30 KB
  int tid = threadIdx.x;
  for (int i = tid; i < 3 * 10 * EMB; i += 256) tab[i] = bond[i];
  __syncthreads();
  int n0 = blockIdx.x * 16;
  for (int nn = 0; nn < 16; ++nn) {
    int n = n0 + nn;
    int e0 = offs[n], e1 = offs[n + 1];
    float acc = 0.f;
    for (int s = e0; s < e1; ++s) {
      float a = csr_adj[s];
      int pk = csr_pack[s];
      int a0 = pk & 255, a1 = (pk >> 8) & 255, a2 = (pk >> 16) & 255;
      acc += a * (tab[a0 * EMB + tid] + tab[(10 + a1) * EMB + tid] + tab[(20 + a2) * EMB + tid]);
    }
    msg[(size_t)n * EMB + tid] = f2bf(acc);
  }
}

// MFMA k-projection, ONE HEAD per block. k = h@Wk + bk, row-normalize,
// write knF (fragment-major), accumulate ks_sum (+h_sum on hd 0).
__global__ __launch_bounds__(256) void k_projk(
    const u16* __restrict__ h_bf, const u16* __restrict__ wkF, const float* __restrict__ bk,
    u16* __restrict__ knF, float* __restrict__ ks_sum, float* __restrict__ h_sum) {
  __shared__ __align__(16) u16 aL[32 * 64 * 8]; // 32 KB
  __shared__ float red[4][EMB];                 // 4 KB
  int tid = threadIdx.x;
  int lane = tid & 63, w = tid >> 6;
  int g = lane >> 4, s = lane & 15;
  int n0 = blockIdx.x * 64;
  int hd = blockIdx.y;
  int wrow = w * 16;
  { // stage A tile from h_bf
    int r = tid & 63, kq = tid >> 6;
#pragma unroll
    for (int ii = 0; ii < 8; ++ii) {
      int k = kq * 64 + ii * 8;
      int row = n0 + r;
      uint4 v = {0u, 0u, 0u, 0u};
      if (row < NN) v = *reinterpret_cast<const uint4*>(h_bf + (size_t)row * EMB + k);
      *reinterpret_cast<uint4*>(&aL[((k >> 3) * 64 + r) * 8]) = v;
    }
  }
  __syncthreads();
  if (hd == 0) { // h_sum once per tile
    float ss = 0.f;
#pragma unroll 8
    for (int r = 0; r < 64; ++r) ss += bf2f(aL[((tid >> 3) * 64 + r) * 8 + (tid & 7)]);
    atomicAdd(&h_sum[tid], ss);
  }
  f32x4 ka[16] = {};
#pragma unroll
  for (int k0 = 0; k0 < 256; k0 += 32) {
    short8 a = ld8(&aL[(((k0 >> 3) + g) * 64 + wrow + s) * 8]);
#pragma unroll
    for (int c = 0; c < 16; ++c) {
      short8 b = ld8(&wkF[(((size_t)(k0 >> 5) * 64 + hd * 16 + c) * 64 + lane) * 8]);
      ka[c] = MFMA16(a, b, ka[c]);
    }
  }
  float nr[4] = {0.f, 0.f, 0.f, 0.f};
#pragma unroll
  for (int c = 0; c < 16; ++c) {
    float bv = bk[hd * 256 + c * 16 + s];
#pragma unroll
    for (int r = 0; r < 4; ++r) {
      ka[c][r] += bv;
      nr[r] += ka[c][r] * ka[c][r];
    }
  }
#pragma unroll
  for (int r = 0; r < 4; ++r) {
    nr[r] += __shfl_xor(nr[r], 1, 64);
    nr[r] += __shfl_xor(nr[r], 2, 64);
    nr[r] += __shfl_xor(nr[r], 4, 64);
    nr[r] += __shfl_xor(nr[r], 8, 64);
  }
  float rn[4];
#pragma unroll
  for (int r = 0; r < 4; ++r) {
    int row = n0 + wrow + g * 4 + r;
    rn[r] = (row < NN && nr[r] > 0.f) ? rsqrtf(nr[r]) : 0.f; // 0 for pad rows
  }
  // write knF fragment-major: value (j = hd*256+c*16+s, n = n0+wrow+g*4+r)
  int nn = wrow + g * 4;
  int nch = (n0 + nn) >> 5;
  int gc = (nn >> 3) & 3;
  int jb = nn & 7; // 0 or 4
  float cs[16];
#pragma unroll
  for (int c = 0; c < 16; ++c) {
    float v0 = ka[c][0] * rn[0], v1 = ka[c][1] * rn[1];
    float v2 = ka[c][2] * rn[2], v3 = ka[c][3] * rn[3];
    cs[c] = v0 + v1 + v2 + v3;
    ushort4 pk;
    pk.x = f2bf(v0); pk.y = f2bf(v1); pk.z = f2bf(v2); pk.w = f2bf(v3);
    *reinterpret_cast<ushort4*>(
        &knF[(((size_t)nch * 64 + hd * 16 + c) * 64 + gc * 16 + s) * 8 + jb]) = pk;
  }
#pragma unroll
  for (int c = 0; c < 16; ++c) {
    cs[c] += __shfl_xor(cs[c], 16, 64);
    cs[c] += __shfl_xor(cs[c], 32, 64);
  }
  if (g == 0) {
#pragma unroll
    for (int c = 0; c < 16; ++c) red[w][c * 16 + s] = cs[c];
  }
  __syncthreads();
  float tot = red[0][tid] + red[1][tid] + red[2][tid] + red[3][tid];
  atomicAdd(&ks_sum[hd * 256 + tid], tot);
}

// MFMA kvs: kvs[j][d] += sum_n knF[j][n] * hF[d][n]; fully coalesced fragments.
__global__ __launch_bounds__(256) void k_kvs(const u16* __restrict__ knF,
                                             const u16* __restrict__ hF,
                                             float* __restrict__ kvs) {
  int tid = threadIdx.x;
  int lane = tid & 63, w = tid >> 6;
  int s = lane & 15, g = lane >> 4;
  int j0 = blockIdx.x * 64;
  int sl = blockIdx.y;
  f32x4 acc[4][4] = {}; // [jf][df]
  for (int ch = sl; ch < NCH; ch += KVS_SL) {
    short8 bfr[4];
#pragma unroll
    for (int df = 0; df < 4; ++df)
      bfr[df] = ld8(&hF[(((size_t)ch * 16 + w * 4 + df) * 64 + lane) * 8]);
#pragma unroll
    for (int jf = 0; jf < 4; ++jf) {
      short8 a = ld8(&knF[(((size_t)ch * 64 + (j0 >> 4) + jf) * 64 + lane) * 8]);
#pragma unroll
      for (int df = 0; df < 4; ++df) acc[jf][df] = MFMA16(a, bfr[df], acc[jf][df]);
    }
  }
#pragma unroll
  for (int jf = 0; jf < 4; ++jf)
#pragma unroll
    for (int df = 0; df < 4; ++df)
#pragma unroll
      for (int r = 0; r < 4; ++r)
        atomicAdd(&kvs[(size_t)(j0 + jf * 16 + g * 4 + r) * EMB + w * 64 + df * 16 + s],
                  acc[jf][df][r]);
}

// M[hd*256+m][o] = sum_d kvs[hd*256+m][d] * fcw[(hd*256+d)*256+o]  (fp32)
__global__ void k_mpre(const float* __restrict__ kvs, const float* __restrict__ fcw,
                       float* __restrict__ M) {
  __shared__ float arow[EMB];
  int bid = blockIdx.x; // hd*256+m
  int hd = bid >> 8;
  int t = threadIdx.x;
  arow[t] = kvs[(size_t)bid * EMB + t];
  __syncthreads();
  float acc = 0.f;
  const float* wp = fcw + (size_t)(hd * 256) * EMB + t;
#pragma unroll 4
  for (int d = 0; d < EMB; ++d) acc += arow[d] * wp[(size_t)d * EMB];
  M[(size_t)bid * EMB + t] = acc;
}

__global__ void k_cvec(const float* __restrict__ h_sum, const float* __restrict__ fcw,
                       float* __restrict__ c) {
  __shared__ float arow[EMB];
  int hd = blockIdx.x;
  int t = threadIdx.x;
  arow[t] = h_sum[t];
  __syncthreads();
  float acc = 0.f;
  const float* wp = fcw + (size_t)(hd * 256) * EMB + t;
#pragma unroll 4
  for (int d = 0; d < EMB; ++d) acc += arow[d] * wp[(size_t)d * EMB];
  c[hd * EMB + t] = acc;
}

// SpMM: wave-per-node, lane owns 4 cols; bf16 in/out, 4-edge unroll.
__global__ __launch_bounds__(256) void k_spmm(
    const u16* __restrict__ xin, const u16* __restrict__ msg,
    const int* __restrict__ offs, const int* __restrict__ csr_col,
    const float* __restrict__ csr_adj, u16* __restrict__ sout) {
  int lane = threadIdx.x & 63, w = threadIdx.x >> 6;
  int n = blockIdx.x * 4 + w;
  if (n >= NN) return;
  int c4 = lane * 4;
  uint2 m = *reinterpret_cast<const uint2*>(msg + (size_t)n * EMB + c4);
  float a0 = bf2f(m.x & 0xffff), a1 = bf2f(m.x >> 16);
  float a2 = bf2f(m.y & 0xffff), a3 = bf2f(m.y >> 16);
  int e0 = offs[n], e1 = offs[n + 1];
  int s = e0;
  for (; s + 4 <= e1; s += 4) {
    int col0 = csr_col[s], col1 = csr_col[s + 1], col2 = csr_col[s + 2], col3 = csr_col[s + 3];
    float w0 = csr_adj[s], w1 = csr_adj[s + 1], w2 = csr_adj[s + 2], w3 = csr_adj[s + 3];
    uint2 r0 = *reinterpret_cast<const uint2*>(xin + (size_t)col0 * EMB + c4);
    uint2 r1 = *reinterpret_cast<const uint2*>(xin + (size_t)col1 * EMB + c4);
    uint2 r2 = *reinterpret_cast<const uint2*>(xin + (size_t)col2 * EMB + c4);
    uint2 r3 = *reinterpret_cast<const uint2*>(xin + (size_t)col3 * EMB + c4);
    a0 += w0 * bf2f(r0.x & 0xffff) + w1 * bf2f(r1.x & 0xffff) + w2 * bf2f(r2.x & 0xffff) + w3 * bf2f(r3.x & 0xffff);
    a1 += w0 * bf2f(r0.x >> 16)    + w1 * bf2f(r1.x >> 16)    + w2 * bf2f(r2.x >> 16)    + w3 * bf2f(r3.x >> 16);
    a2 += w0 * bf2f(r0.y & 0xffff) + w1 * bf2f(r1.y & 0xffff) + w2 * bf2f(r2.y & 0xffff) + w3 * bf2f(r3.y & 0xffff);
    a3 += w0 * bf2f(r0.y >> 16)    + w1 * bf2f(r1.y >> 16)    + w2 * bf2f(r2.y >> 16)    + w3 * bf2f(r3.y >> 16);
  }
  for (; s < e1; ++s) {
    int col = csr_col[s];
    float wv = csr_adj[s];
    uint2 r0 = *reinterpret_cast<const uint2*>(xin + (size_t)col * EMB + c4);
    a0 += wv * bf2f(r0.x & 0xffff);
    a1 += wv * bf2f(r0.x >> 16);
    a2 += wv * bf2f(r0.y & 0xffff);
    a3 += wv * bf2f(r0.y >> 16);
  }
  ushort4 o;
  o.x = f2bf(a0); o.y = f2bf(a1); o.z = f2bf(a2); o.w = f2bf(a3);
  *reinterpret_cast<ushort4*>(sout + (size_t)n * EMB + c4) = o;
}

// MFMA fused layer tail (round-6 structure, coalesced fragment loads).
__global__ __launch_bounds__(256) void k_fused(
    u16* __restrict__ h_bf,
    const u16* __restrict__ s1, const u16* __restrict__ s2, const u16* __restrict__ s3,
    const u16* __restrict__ wqF, const float* __restrict__ bq,
    const u16* __restrict__ MTF, const float* __restrict__ cvec, const float* __restrict__ kss,
    const u16* __restrict__ fcwF, const float* __restrict__ fcb,
    const float* __restrict__ lg, const float* __restrict__ lb) {
  __shared__ __align__(16) u16 aL[32 * 64 * 8]; // 32 KB
  __shared__ __align__(16) u16 qL[16 * 64 * 8]; // 16 KB (one m-half)
  int tid = threadIdx.x;
  int lane = tid & 63, w = tid >> 6;
  int g = lane >> 4, s = lane & 15;
  int n0 = blockIdx.x * 64;
  int wrow = w * 16;
  { // stage h tile
    int r = tid & 63, kq = tid >> 6;
#pragma unroll
    for (int ii = 0; ii < 8; ++ii) {
      int k = kq * 64 + ii * 8;
      int row = n0 + r;
      uint4 v = {0u, 0u, 0u, 0u};
      if (row < NN) v = *reinterpret_cast<const uint4*>(h_bf + (size_t)row * EMB + k);
      *reinterpret_cast<uint4*>(&aL[((k >> 3) * 64 + r) * 8]) = v;
    }
  }
  __syncthreads();

  // residual init from staged h
  f32x4 zac[16];
#pragma unroll
  for (int c = 0; c < 16; ++c) {
    int col = c * 16 + s;
#pragma unroll
    for (int r = 0; r < 4; ++r)
      zac[c][r] = bf2f(aL[((col >> 3) * 64 + wrow + g * 4 + r) * 8 + (col & 7)]);
  }

  // ---- attention ----
  for (int hd = 0; hd < NH; ++hd) {
    f32x4 qa[16] = {};
#pragma unroll
    for (int k0 = 0; k0 < 256; k0 += 32) {
      short8 a = ld8(&aL[(((k0 >> 3) + g) * 64 + wrow + s) * 8]);
#pragma unroll
      for (int c = 0; c < 16; ++c) {
        short8 b = ld8(&wqF[(((size_t)(k0 >> 5) * 64 + hd * 16 + c) * 64 + lane) * 8]);
        qa[c] = MFMA16(a, b, qa[c]);
      }
    }
    float nr[4] = {0.f, 0.f, 0.f, 0.f};
    float dp[4] = {0.f, 0.f, 0.f, 0.f};
#pragma unroll
    for (int c = 0; c < 16; ++c) {
      float bv = bq[hd * 256 + c * 16 + s];
      float kv = kss[hd * 256 + c * 16 + s];
#pragma unroll
      for (int r = 0; r < 4; ++r) {
        qa[c][r] += bv;
        nr[r] += qa[c][r] * qa[c][r];
        dp[r] += qa[c][r] * kv;
      }
    }
#pragma unroll
    for (int r = 0; r < 4; ++r) {
      nr[r] += __shfl_xor(nr[r], 1, 64);
      nr[r] += __shfl_xor(nr[r], 2, 64);
      nr[r] += __shfl_xor(nr[r], 4, 64);
      nr[r] += __shfl_xor(nr[r], 8, 64);
      dp[r] += __shfl_xor(dp[r], 1, 64);
      dp[r] += __shfl_xor(dp[r], 2, 64);
      dp[r] += __shfl_xor(dp[r], 4, 64);
      dp[r] += __shfl_xor(dp[r], 8, 64);
    }
    float sc[4], rdv[4];
#pragma unroll
    for (int r = 0; r < 4; ++r) {
      int row = n0 + wrow + g * 4 + r;
      float rn = (row < NN && nr[r] > 0.f) ? rsqrtf(nr[r]) : 0.f;
      rdv[r] = 1.f / (dp[r] * rn + (float)NN);
      sc[r] = rn * rdv[r];
    }
    // PV in two m-halves (qL holds 128 m at a time)
#pragma unroll
    for (int hh = 0; hh < 2; ++hh) {
      __syncthreads();
#pragma unroll
      for (int c = hh * 8; c < hh * 8 + 8; ++c) {
        int mh = (c - hh * 8) * 16 + s;
#pragma unroll
        for (int r = 0; r < 4; ++r)
          qL[((mh >> 3) * 64 + wrow + g * 4 + r) * 8 + (mh & 7)] = f2bf(qa[c][r] * sc[r]);
      }
      __syncthreads();
#pragma unroll
      for (int k0 = 0; k0 < 128; k0 += 32) {
        short8 a = ld8(&qL[(((k0 >> 3) + g) * 64 + wrow + s) * 8]);
#pragma unroll
        for (int c = 0; c < 16; ++c) {
          short8 b = ld8(&MTF[(((size_t)((hh * 128 + k0) >> 5) * 64 + hd * 16 + c) * 64 + lane) * 8]);
          zac[c] = MFMA16(a, b, zac[c]);
        }
      }
    }
#pragma unroll
    for (int c = 0; c < 16; ++c) {
      float cv = cvec[hd * 256 + c * 16 + s];
#pragma unroll
      for (int r = 0; r < 4; ++r) zac[c][r] += cv * rdv[r];
    }
  }

  // ---- x2 = [h|s1|s2|s3] @ fcw[1024:2048] ----
  for (int sg = 0; sg < 4; ++sg) {
    if (sg > 0) {
      const u16* sp = (sg == 1) ? s1 : (sg == 2) ? s2 : s3;
      __syncthreads();
      int r = tid & 63, kq = tid >> 6;
#pragma unroll
      for (int ii = 0; ii < 8; ++ii) {
        int k = kq * 64 + ii * 8;
        int row = n0 + r;
        uint4 v = {0u, 0u, 0u, 0u};
        if (row < NN) v = *reinterpret_cast<const uint4*>(sp + (size_t)row * EMB + k);
        *reinterpret_cast<uint4*>(&aL[((k >> 3) * 64 + r) * 8]) = v;
      }
      __syncthreads();
    }
#pragma unroll
    for (int k0 = 0; k0 < 256; k0 += 32) {
      short8 a = ld8(&aL[(((k0 >> 3) + g) * 64 + wrow + s) * 8]);
#pragma unroll
      for (int c = 0; c < 16; ++c) {
        short8 b = ld8(&fcwF[(((size_t)(32 + sg * 8 + (k0 >> 5)) * 16 + c) * 64 + lane) * 8]);
        zac[c] = MFMA16(a, b, zac[c]);
      }
    }
  }

  // ---- epilogue: + fc_b, LN, relu, store h_bf ----
  float sm[4] = {0.f, 0.f, 0.f, 0.f}, sq[4] = {0.f, 0.f, 0.f, 0.f};
#pragma unroll
  for (int c = 0; c < 16; ++c) {
    int col = c * 16 + s;
    float fb = fcb[col];
#pragma unroll
    for (int r = 0; r < 4; ++r) {
      float v = zac[c][r] + fb;
      zac[c][r] = v;
      sm[r] += v;
      sq[r] += v * v;
    }
  }
#pragma unroll
  for (int r = 0; r < 4; ++r) {
    sm[r] += __shfl_xor(sm[r], 1, 64);
    sm[r] += __shfl_xor(sm[r], 2, 64);
    sm[r] += __shfl_xor(sm[r], 4, 64);
    sm[r] += __shfl_xor(sm[r], 8, 64);
    sq[r] += __shfl_xor(sq[r], 1, 64);
    sq[r] += __shfl_xor(sq[r], 2, 64);
    sq[r] += __shfl_xor(sq[r], 4, 64);
    sq[r] += __shfl_xor(sq[r], 8, 64);
  }
  float mu[4], rs[4];
#pragma unroll
  for (int r = 0; r < 4; ++r) {
    mu[r] = sm[r] * (1.f / 256.f);
    float var = sq[r] * (1.f / 256.f) - mu[r] * mu[r];
    rs[r] = rsqrtf(var + 1e-5f);
  }
#pragma unroll
  for (int c = 0; c < 16; ++c) {
    int col = c * 16 + s;
    float gg = lg[col], bb = lb[col];
#pragma unroll
    for (int r = 0; r < 4; ++r) {
      int row = n0 + wrow + g * 4 + r;
      if (row < NN) {
        float o = fmaxf(0.f, (zac[c][r] - mu[r]) * rs[r] * gg + bb);
        h_bf[(size_t)row * EMB + col] = f2bf(o);
      }
    }
  }
}

// ---------------- pooling / output ----------------

__global__ void k_pool(const u16* __restrict__ h_bf, const int* __restrict__ batch,
                       float* __restrict__ pooled) {
  int t = threadIdx.x; // col
  int n0 = blockIdx.x * 64;
  if (n0 >= NN) return;
  int nend = n0 + 64;
  if (nend > NN) nend = NN;
  float run = 0.f;
  int cur = batch[n0];
  for (int n = n0; n < nend; ++n) {
    int b = batch[n];
    if (b != cur) {
      atomicAdd(&pooled[(size_t)cur * EMB + t], run);
      run = 0.f;
      cur = b;
    }
    run += bf2f(h_bf[(size_t)n * EMB + t]);
  }
  atomicAdd(&pooled[(size_t)cur * EMB + t], run);
}

__global__ void k_out(const float* __restrict__ pooled, const float* __restrict__ gcnt,
                      const float* __restrict__ ow, const float* __restrict__ ob,
                      float* __restrict__ out) {
  __shared__ float prow[EMB];
  int g = blockIdx.x, t = threadIdx.x;
  float rc = 1.f / fmaxf(gcnt[g], 1.f);
  for (int i = t; i < EMB; i += TASKS) prow[i] = pooled[(size_t)g * EMB + i] * rc;
  __syncthreads();
  float acc = ob[t];
#pragma unroll 4
  for (int d = 0; d < EMB; ++d) acc += prow[d] * ow[d * TASKS + t];
  out[(size_t)g * TASKS + t] = acc;
}

// ---------------- launch ----------------

extern "C" void kernel_launch(void* const* d_in, const int* in_sizes, int n_in,
                              void* d_out, int out_size, void* d_ws, size_t ws_size,
                              hipStream_t stream) {
  const int* x = (const int*)d_in[0];
  const int* eidx = (const int*)d_in[1];
  const int* eattr = (const int*)d_in[2];
  const int* batch = (const int*)d_in[3];
  const float* aemb = (const float*)d_in[4];
  const float* bemb = (const float*)d_in[5];
  const float* wq = (const float*)d_in[6];
  const float* bq = (const float*)d_in[7];
  const float* wk = (const float*)d_in[8];
  const float* bk = (const float*)d_in[9];
  const float* fcw = (const float*)d_in[10];
  const float* fcb = (const float*)d_in[11];
  const float* lg = (const float*)d_in[12];
  const float* lb = (const float*)d_in[13];
  const float* ow = (const float*)d_in[14];
  const float* ob = (const float*)d_in[15];
  float* out = (float*)d_out;

  size_t off = 0;
  auto alloc = [&](size_t bytes) -> void* {
    void* r = (char*)d_ws + off;
    off += (bytes + 255) & ~(size_t)255;
    return r;
  };
  u16* h_bf = (u16*)alloc((size_t)NN * EMB * 2);        // 25.6 MB
  u16* region = (u16*)alloc((size_t)HE * NS * 2);       // 102.5 MB (knF | msg,s1,s2,s3)
  u16* knF = region;
  u16* msg = region;
  u16* s1 = region + (size_t)NN * EMB;
  u16* s2 = region + (size_t)2 * NN * EMB;
  u16* s3 = region + (size_t)3 * NN * EMB;
  u16* hF = (u16*)alloc((size_t)EMB * NS * 2);          // 25.6 MB
  float* kvs = (float*)alloc((size_t)HE * EMB * 4);     // 1 MB
  float* Mm = (float*)alloc((size_t)HE * EMB * 4);      // 1 MB
  u16* MTF = (u16*)alloc((size_t)HE * EMB * 2);         // 0.5 MB
  u16* wqF = (u16*)alloc((size_t)NL * HE * EMB * 2);    // 2.1 MB
  u16* wkF = (u16*)alloc((size_t)NL * HE * EMB * 2);    // 2.1 MB
  u16* fcwF = (u16*)alloc((size_t)NL * 2048 * EMB * 2); // 4.2 MB
  float* cvec = (float*)alloc((size_t)NH * EMB * 4);
  float* ksh = (float*)alloc((size_t)(HE + EMB) * 4); // ks_sum | h_sum
  float* ks_sum = ksh;
  float* h_sum = ksh + HE;
  float* dinv_i = (float*)alloc((size_t)NN * 4);
  float* dinv_j = (float*)alloc((size_t)NN * 4);
  int* deg_i = (int*)alloc((size_t)NN * 4);
  int* deg_j = (int*)alloc((size_t)NN * 4);
  int* offs = (int*)alloc((size_t)(NN + 1) * 4);
  int* cursor = (int*)alloc((size_t)NN * 4);
  int* csr_col = (int*)alloc((size_t)NE * 4);
  float* csr_adj = (float*)alloc((size_t)NE * 4);
  int* csr_pack = (int*)alloc((size_t)NE * 4);
  float* pooled = (float*)alloc((size_t)NG * EMB * 4);
  float* gcnt = (float*)alloc((size_t)NG * 4);

  if (off > ws_size) {
    k_fill<<<(out_size + 255) / 256, 256, 0, stream>>>(out, out_size, 1048576.f);
    return;
  }

  const int* row = eidx;
  const int* colp = eidx + NE;

  k_zero<<<(NN + 255) / 256, 256, 0, stream>>>((u32*)deg_i, NN);
  k_zero<<<(NN + 255) / 256, 256, 0, stream>>>((u32*)deg_j, NN);
  k_zero<<<(NN + 255) / 256, 256, 0, stream>>>((u32*)cursor, NN);
  k_zero<<<(NG + 255) / 256, 256, 0, stream>>>((u32*)gcnt, NG);
  k_zero<<<(NG * EMB + 255) / 256, 256, 0, stream>>>((u32*)pooled, NG * EMB);

  // one-time fragment-major weight packs
  k_frag<<<dim3(8, 64, NL), 64, 0, stream>>>(wq, wqF, 1024, 64, 0,
                                             (long)EMB * HE, (long)HE * EMB);
  k_frag<<<dim3(8, 64, NL), 64, 0, stream>>>(wk, wkF, 1024, 64, 0,
                                             (long)EMB * HE, (long)HE * EMB);
  k_frag<<<dim3(64, 16, NL), 64, 0, stream>>>(fcw, fcwF, 256, 16, 0,
                                              (long)2048 * EMB, (long)2048 * EMB);

  k_atom<<<NN, EMB, 0, stream>>>(x, aemb, h_bf);
  k_deg<<<NE / 256, 256, 0, stream>>>(row, colp, deg_i, deg_j);
  k_dinv<<<(NN + 255) / 256, 256, 0, stream>>>(deg_i, deg_j, dinv_i, dinv_j);
  k_scan<<<1, 1024, 0, stream>>>(deg_i, offs);
  k_csr<<<NE / 256, 256, 0, stream>>>(row, colp, eattr, dinv_i, dinv_j, offs, cursor,
                                      csr_col, csr_adj, csr_pack);
  k_gcnt<<<(NN + 255) / 256, 256, 0, stream>>>(batch, gcnt);

  for (int l = 0; l < NL; ++l) {
    const float* fcw_l = fcw + (size_t)l * 2048 * EMB;
    k_zero<<<(HE + EMB + 255) / 256, 256, 0, stream>>>((u32*)ksh, HE + EMB);
    k_zero<<<(HE * EMB + 255) / 256, 256, 0, stream>>>((u32*)kvs, HE * EMB);
    // --- phase 1: region holds knF ---
    k_projk<<<dim3(GB64, NH), 256, 0, stream>>>(h_bf, wkF + (size_t)l * HE * EMB,
                                                bk + (size_t)l * HE, knF, ks_sum, h_sum);
    k_htrf<<<dim3(GB64, 4), 256, 0, stream>>>(h_bf, hF);
    k_kvs<<<dim3(16, KVS_SL), 256, 0, stream>>>(knF, hF, kvs);
    k_mpre<<<HE, 256, 0, stream>>>(kvs, fcw_l, Mm);
    k_frag<<<dim3(8, 16, NH), 64, 0, stream>>>(Mm, MTF, 256, 64, 16,
                                               (long)EMB * EMB, 0);
    k_cvec<<<NH, 256, 0, stream>>>(h_sum, fcw_l, cvec);
    // --- phase 2: knF dead; region becomes msg/s1/s2/s3 ---
    k_message<<<NN / 16, 256, 0, stream>>>(bemb + (size_t)l * 3 * 10 * EMB, offs, csr_adj,
                                           csr_pack, msg);
    k_spmm<<<NN / 4, 256, 0, stream>>>(h_bf, msg, offs, csr_col, csr_adj, s1);
    k_spmm<<<NN / 4, 256, 0, stream>>>(s1, msg, offs, csr_col, csr_adj, s2);
    k_spmm<<<NN / 4, 256, 0, stream>>>(s2, msg, offs, csr_col, csr_adj, s3);
    k_fused<<<GB64, 256, 0, stream>>>(h_bf, s1, s2, s3, wqF + (size_t)l * HE * EMB,
                                      bq + (size_t)l * HE, MTF, cvec, ks_sum,
                                      fcwF + (size_t)l * 2048 * EMB, fcb + (size_t)l * EMB,
                                      lg + (size_t)l * EMB, lb + (size_t)l * EMB);
  }
  k_pool<<<(NN + 63) / 64, 256, 0, stream>>>(h_bf, batch, pooled);
  k_out<<<NG, TASKS, 0, stream>>>(pooled, gcnt, ow, ob, out);
}

// Round 9
// 4049.630 us; speedup vs baseline: 1.8132x; 1.1003x over previous
//
#include <hip/hip_runtime.h>

#define DEV __device__ __forceinline__

constexpr int NN = 50000;
constexpr int NE = 800000;
constexpr int NG = 1024;
constexpr int EMB = 256;
constexpr int NH = 4;
constexpr int HE = 1024;   // NH*EMB
constexpr int NL = 4;
constexpr int TASKS = 128;
constexpr int NS = 50048;            // padded nodes (multiple of 64)
constexpr int NCH = NS / 32;         // 1564 K-chunks for kvs
constexpr int KVS_SL = 64;           // kvs n-slices (TLP)
constexpr int GB64 = NS / 64;        // 782

using u16 = unsigned short;
using u32 = unsigned int;

typedef __attribute__((ext_vector_type(8))) short short8;
typedef __attribute__((ext_vector_type(4))) float f32x4;

#define MFMA16(a8, b8, c4) __builtin_amdgcn_mfma_f32_16x16x32_bf16(a8, b8, c4, 0, 0, 0)

DEV u16 f2bf(float f) {
  u32 u = __float_as_uint(f);
  u32 r = (u + 0x7FFFu + ((u >> 16) & 1u)) >> 16;
  return (u16)r;
}
DEV float bf2f(u16 s) { return __uint_as_float(((u32)s) << 16); }
DEV short8 ld8(const u16* p) { return *reinterpret_cast<const short8*>(p); }

// async global->LDS, 16B per lane; LDS dst is wave-uniform base + lane*16
DEV void gld16(const u16* g, u16* l) {
  __builtin_amdgcn_global_load_lds(
      (const __attribute__((address_space(1))) void*)g,
      (__attribute__((address_space(3))) void*)l, 16, 0, 0);
}

// stage one k-step of B (16 fragments x 1KB); wave w stages frags 4w..4w+3
DEV void stage16(const u16* __restrict__ src, u16* dst, int w, int lane) {
#pragma unroll
  for (int i = 0; i < 4; ++i) {
    int f = w * 4 + i;
    gld16(src + (size_t)f * 512 + lane * 8, dst + f * 512);
  }
}

// stage a 64-row x 256-col bf16 A tile into aL layout [(k>>3)*64 + row][8]
// UNGUARDED: pad rows read in-ws garbage; row-local through MFMA, never stored.
DEV void stage_rows(const u16* __restrict__ src, u16* dst, int n0, int w, int lane) {
#pragma unroll
  for (int ii = 0; ii < 8; ++ii) {
    int kc = w * 8 + ii;
    gld16(src + (size_t)(n0 + lane) * EMB + kc * 8, dst + kc * 512);
  }
}

// B-fragment source for virtual k-step of k_fused (96 steps)
DEV const u16* bsrc(int step, const u16* wqF, const u16* MTF, const u16* fcwF) {
  if (step > 95) step = 95;
  if (step < 64) {
    int hd = step >> 4, t = step & 15;
    if (t < 8) return wqF + ((size_t)(t * 64 + hd * 16)) * 512;
    return MTF + ((size_t)((t - 8) * 64 + hd * 16)) * 512;
  }
  return fcwF + ((size_t)(32 + (step - 64)) * 16) * 512;
}

// ---------------- utility ----------------

__global__ void k_zero(u32* __restrict__ p, int n) {
  int i = blockIdx.x * 256 + threadIdx.x;
  if (i < n) p[i] = 0u;
}

__global__ void k_fill(float* __restrict__ p, int n, float v) {
  int i = blockIdx.x * 256 + threadIdx.x;
  if (i < n) p[i] = v;
}

// Pack a [K][R] f32 matrix into MFMA B-fragment-major bf16.
__global__ void k_frag(const float* __restrict__ in, u16* __restrict__ outp,
                       int R, int rqTot, int rqStep, long inStride, long outStride) {
  int nc = blockIdx.x, rq = blockIdx.y, b = blockIdx.z;
  int l = threadIdx.x & 63;
  int g = l >> 4, s = l & 15;
  const float* ip = in + (size_t)b * inStride + (size_t)(nc * 32 + g * 8) * R + rq * 16 + s;
  short8 v;
#pragma unroll
  for (int j = 0; j < 8; ++j) v[j] = (short)f2bf(ip[(size_t)j * R]);
  u16* op = outp + (size_t)b * outStride +
            ((size_t)(nc * rqTot + b * rqStep + rq) * 64 + l) * 8;
  *reinterpret_cast<short8*>(op) = v;
}

// h -> fragment-major hF (K = node dim, rows = d).  Zero-padded to NS.
__global__ void k_htrf(const u16* __restrict__ h_bf, u16* __restrict__ hF) {
  __shared__ u16 t[64][72];
  int tid = threadIdx.x;
  int n0 = blockIdx.x * 64, d0 = blockIdx.y * 64;
#pragma unroll
  for (int rr = 0; rr < 2; ++rr) {
    int nl = rr * 32 + (tid >> 3);
    int dd = (tid & 7) * 8;
    uint4 v = {0u, 0u, 0u, 0u};
    int n = n0 + nl;
    if (n < NN) v = *reinterpret_cast<const uint4*>(h_bf + (size_t)n * EMB + d0 + dd);
    *reinterpret_cast<uint4*>(&t[nl][dd]) = v;
  }
  __syncthreads();
#pragma unroll
  for (int k = 0; k < 2; ++k) {
    int u = tid + 256 * k;          // 512 output ushort8 units
    int nchL = u >> 8;              // 0..1
    int rqL = (u >> 6) & 3;         // 0..3
    int l = u & 63;
    int g = l >> 4, s = l & 15;
    short8 v;
#pragma unroll
    for (int j = 0; j < 8; ++j) v[j] = (short)t[nchL * 32 + g * 8 + j][rqL * 16 + s];
    *reinterpret_cast<short8*>(
        &hF[(((size_t)((n0 >> 5) + nchL) * 16 + (d0 >> 4) + rqL) * 64 + l) * 8]) = v;
  }
}

// ---------------- setup kernels ----------------

__global__ void k_atom(const int* __restrict__ x, const float* __restrict__ aemb,
                       u16* __restrict__ h_bf) {
  int n = blockIdx.x, d = threadIdx.x;
  const int* xr = x + n * 9;
  float acc = 0.f;
#pragma unroll
  for (int f = 0; f < 9; ++f) acc += aemb[(f * 100 + xr[f]) * EMB + d];
  h_bf[(size_t)n * EMB + d] = f2bf(acc);
}

__global__ void k_deg(const int* __restrict__ row, const int* __restrict__ col,
                      int* __restrict__ deg_i, int* __restrict__ deg_j) {
  int e = blockIdx.x * 256 + threadIdx.x;
  if (e < NE) {
    atomicAdd(&deg_i[row[e]], 1);
    atomicAdd(&deg_j[col[e]], 1);
  }
}

__global__ void k_dinv(const int* __restrict__ deg_i, const int* __restrict__ deg_j,
                       float* __restrict__ di, float* __restrict__ dj) {
  int n = blockIdx.x * 256 + threadIdx.x;
  if (n < NN) {
    di[n] = deg_i[n] > 0 ? rsqrtf((float)deg_i[n]) : 0.f;
    dj[n] = deg_j[n] > 0 ? rsqrtf((float)deg_j[n]) : 0.f;
  }
}

__global__ void k_scan(const int* __restrict__ deg, int* __restrict__ offs) {
  __shared__ int tot[1024];
  int t = threadIdx.x;
  constexpr int PER = (NN + 1023) / 1024; // 49
  int lo = t * PER, hi = lo + PER;
  if (hi > NN) hi = NN;
  int s = 0;
  for (int i = lo; i < hi; ++i) s += deg[i];
  tot[t] = s;
  __syncthreads();
  for (int off = 1; off < 1024; off <<= 1) {
    int v = (t >= off) ? tot[t - off] : 0;
    __syncthreads();
    tot[t] += v;
    __syncthreads();
  }
  int run = (t == 0) ? 0 : tot[t - 1];
  for (int i = lo; i < hi; ++i) { offs[i] = run; run += deg[i]; }
  if (t == 0) offs[NN] = NE;
}

__global__ void k_csr(const int* __restrict__ row, const int* __restrict__ col,
                      const int* __restrict__ eattr, const float* __restrict__ di,
                      const float* __restrict__ dj, const int* __restrict__ offs,
                      int* __restrict__ cursor, int* __restrict__ csr_col,
                      float* __restrict__ csr_adj, int* __restrict__ csr_pack) {
  int e = blockIdx.x * 256 + threadIdx.x;
  if (e >= NE) return;
  int r = row[e], c = col[e];
  int slot = offs[r] + atomicAdd(&cursor[r], 1);
  csr_col[slot] = c;
  csr_adj[slot] = di[r] * dj[c];
  csr_pack[slot] = eattr[e * 3] | (eattr[e * 3 + 1] << 8) | (eattr[e * 3 + 2] << 16);
}

__global__ void k_gcnt(const int* __restrict__ batch, float* __restrict__ gcnt) {
  int n = blockIdx.x * 256 + threadIdx.x;
  if (n < NN) atomicAdd(&gcnt[batch[n]], 1.f);
}

// ---------------- per-layer kernels ----------------

__global__ void k_message(const float* __restrict__ bond, const int* __restrict__ offs,
                          const float* __restrict__ csr_adj, const int* __restrict__ csr_pack,
                          u16* __restrict__ msg) {
  __shared__ float tab[3 * 10 * EMB]; // 30 KB
  int tid = threadIdx.x;
  for (int i = tid; i < 3 * 10 * EMB; i += 256) tab[i] = bond[i];
  __syncthreads();
  int n0 = blockIdx.x * 16;
  for (int nn = 0; nn < 16; ++nn) {
    int n = n0 + nn;
    int e0 = offs[n], e1 = offs[n + 1];
    float acc = 0.f;
    for (int s = e0; s < e1; ++s) {
      float a = csr_adj[s];
      int pk = csr_pack[s];
      int a0 = pk & 255, a1 = (pk >> 8) & 255, a2 = (pk >> 16) & 255;
      acc += a * (tab[a0 * EMB + tid] + tab[(10 + a1) * EMB + tid] + tab[(20 + a2) * EMB + tid]);
    }
    msg[(size_t)n * EMB + tid] = f2bf(acc);
  }
}

// MFMA k-projection, ONE HEAD per block. k = h@Wk + bk, row-normalize,
// write knF (fragment-major), accumulate ks_sum (+h_sum on hd 0).
__global__ __launch_bounds__(256) void k_projk(
    const u16* __restrict__ h_bf, const u16* __restrict__ wkF, const float* __restrict__ bk,
    u16* __restrict__ knF, float* __restrict__ ks_sum, float* __restrict__ h_sum) {
  __shared__ __align__(16) u16 aL[32 * 64 * 8]; // 32 KB
  __shared__ float red[4][EMB];                 // 4 KB
  int tid = threadIdx.x;
  int lane = tid & 63, w = tid >> 6;
  int g = lane >> 4, s = lane & 15;
  int n0 = blockIdx.x * 64;
  int hd = blockIdx.y;
  int wrow = w * 16;
  { // stage A tile from h_bf (guarded: knF pads must be exactly zero)
    int r = tid & 63, kq = tid >> 6;
#pragma unroll
    for (int ii = 0; ii < 8; ++ii) {
      int k = kq * 64 + ii * 8;
      int row = n0 + r;
      uint4 v = {0u, 0u, 0u, 0u};
      if (row < NN) v = *reinterpret_cast<const uint4*>(h_bf + (size_t)row * EMB + k);
      *reinterpret_cast<uint4*>(&aL[((k >> 3) * 64 + r) * 8]) = v;
    }
  }
  __syncthreads();
  if (hd == 0) { // h_sum once per tile
    float ss = 0.f;
#pragma unroll 8
    for (int r = 0; r < 64; ++r) ss += bf2f(aL[((tid >> 3) * 64 + r) * 8 + (tid & 7)]);
    atomicAdd(&h_sum[tid], ss);
  }
  f32x4 ka[16] = {};
#pragma unroll
  for (int k0 = 0; k0 < 256; k0 += 32) {
    short8 a = ld8(&aL[(((k0 >> 3) + g) * 64 + wrow + s) * 8]);
#pragma unroll
    for (int c = 0; c < 16; ++c) {
      short8 b = ld8(&wkF[(((size_t)(k0 >> 5) * 64 + hd * 16 + c) * 64 + lane) * 8]);
      ka[c] = MFMA16(a, b, ka[c]);
    }
  }
  float nr[4] = {0.f, 0.f, 0.f, 0.f};
#pragma unroll
  for (int c = 0; c < 16; ++c) {
    float bv = bk[hd * 256 + c * 16 + s];
#pragma unroll
    for (int r = 0; r < 4; ++r) {
      ka[c][r] += bv;
      nr[r] += ka[c][r] * ka[c][r];
    }
  }
#pragma unroll
  for (int r = 0; r < 4; ++r) {
    nr[r] += __shfl_xor(nr[r], 1, 64);
    nr[r] += __shfl_xor(nr[r], 2, 64);
    nr[r] += __shfl_xor(nr[r], 4, 64);
    nr[r] += __shfl_xor(nr[r], 8, 64);
  }
  float rn[4];
#pragma unroll
  for (int r = 0; r < 4; ++r) {
    int row = n0 + wrow + g * 4 + r;
    rn[r] = (row < NN && nr[r] > 0.f) ? rsqrtf(nr[r]) : 0.f; // 0 for pad rows
  }
  int nn = wrow + g * 4;
  int nch = (n0 + nn) >> 5;
  int gc = (nn >> 3) & 3;
  int jb = nn & 7; // 0 or 4
  float cs[16];
#pragma unroll
  for (int c = 0; c < 16; ++c) {
    float v0 = ka[c][0] * rn[0], v1 = ka[c][1] * rn[1];
    float v2 = ka[c][2] * rn[2], v3 = ka[c][3] * rn[3];
    cs[c] = v0 + v1 + v2 + v3;
    ushort4 pk;
    pk.x = f2bf(v0); pk.y = f2bf(v1); pk.z = f2bf(v2); pk.w = f2bf(v3);
    *reinterpret_cast<ushort4*>(
        &knF[(((size_t)nch * 64 + hd * 16 + c) * 64 + gc * 16 + s) * 8 + jb]) = pk;
  }
#pragma unroll
  for (int c = 0; c < 16; ++c) {
    cs[c] += __shfl_xor(cs[c], 16, 64);
    cs[c] += __shfl_xor(cs[c], 32, 64);
  }
  if (g == 0) {
#pragma unroll
    for (int c = 0; c < 16; ++c) red[w][c * 16 + s] = cs[c];
  }
  __syncthreads();
  float tot = red[0][tid] + red[1][tid] + red[2][tid] + red[3][tid];
  atomicAdd(&ks_sum[hd * 256 + tid], tot);
}

// MFMA kvs: kvs[j][d] += sum_n knF[j][n] * hF[d][n]; fully coalesced fragments.
__global__ __launch_bounds__(256) void k_kvs(const u16* __restrict__ knF,
                                             const u16* __restrict__ hF,
                                             float* __restrict__ kvs) {
  int tid = threadIdx.x;
  int lane = tid & 63, w = tid >> 6;
  int s = lane & 15, g = lane >> 4;
  int j0 = blockIdx.x * 64;
  int sl = blockIdx.y;
  f32x4 acc[4][4] = {}; // [jf][df]
  for (int ch = sl; ch < NCH; ch += KVS_SL) {
    short8 bfr[4];
#pragma unroll
    for (int df = 0; df < 4; ++df)
      bfr[df] = ld8(&hF[(((size_t)ch * 16 + w * 4 + df) * 64 + lane) * 8]);
#pragma unroll
    for (int jf = 0; jf < 4; ++jf) {
      short8 a = ld8(&knF[(((size_t)ch * 64 + (j0 >> 4) + jf) * 64 + lane) * 8]);
#pragma unroll
      for (int df = 0; df < 4; ++df) acc[jf][df] = MFMA16(a, bfr[df], acc[jf][df]);
    }
  }
#pragma unroll
  for (int jf = 0; jf < 4; ++jf)
#pragma unroll
    for (int df = 0; df < 4; ++df)
#pragma unroll
      for (int r = 0; r < 4; ++r)
        atomicAdd(&kvs[(size_t)(j0 + jf * 16 + g * 4 + r) * EMB + w * 64 + df * 16 + s],
                  acc[jf][df][r]);
}

// M[hd*256+m][o] = sum_d kvs[hd*256+m][d] * fcw[(hd*256+d)*256+o]  (fp32)
__global__ void k_mpre(const float* __restrict__ kvs, const float* __restrict__ fcw,
                       float* __restrict__ M) {
  __shared__ float arow[EMB];
  int bid = blockIdx.x; // hd*256+m
  int hd = bid >> 8;
  int t = threadIdx.x;
  arow[t] = kvs[(size_t)bid * EMB + t];
  __syncthreads();
  float acc = 0.f;
  const float* wp = fcw + (size_t)(hd * 256) * EMB + t;
#pragma unroll 4
  for (int d = 0; d < EMB; ++d) acc += arow[d] * wp[(size_t)d * EMB];
  M[(size_t)bid * EMB + t] = acc;
}

__global__ void k_cvec(const float* __restrict__ h_sum, const float* __restrict__ fcw,
                       float* __restrict__ c) {
  __shared__ float arow[EMB];
  int hd = blockIdx.x;
  int t = threadIdx.x;
  arow[t] = h_sum[t];
  __syncthreads();
  float acc = 0.f;
  const float* wp = fcw + (size_t)(hd * 256) * EMB + t;
#pragma unroll 4
  for (int d = 0; d < EMB; ++d) acc += arow[d] * wp[(size_t)d * EMB];
  c[hd * EMB + t] = acc;
}

// SpMM: wave-per-node, lane owns 4 cols; bf16 in/out, 4-edge unroll.
__global__ __launch_bounds__(256) void k_spmm(
    const u16* __restrict__ xin, const u16* __restrict__ msg,
    const int* __restrict__ offs, const int* __restrict__ csr_col,
    const float* __restrict__ csr_adj, u16* __restrict__ sout) {
  int lane = threadIdx.x & 63, w = threadIdx.x >> 6;
  int n = blockIdx.x * 4 + w;
  if (n >= NN) return;
  int c4 = lane * 4;
  uint2 m = *reinterpret_cast<const uint2*>(msg + (size_t)n * EMB + c4);
  float a0 = bf2f(m.x & 0xffff), a1 = bf2f(m.x >> 16);
  float a2 = bf2f(m.y & 0xffff), a3 = bf2f(m.y >> 16);
  int e0 = offs[n], e1 = offs[n + 1];
  int s = e0;
  for (; s + 4 <= e1; s += 4) {
    int col0 = csr_col[s], col1 = csr_col[s + 1], col2 = csr_col[s + 2], col3 = csr_col[s + 3];
    float w0 = csr_adj[s], w1 = csr_adj[s + 1], w2 = csr_adj[s + 2], w3 = csr_adj[s + 3];
    uint2 r0 = *reinterpret_cast<const uint2*>(xin + (size_t)col0 * EMB + c4);
    uint2 r1 = *reinterpret_cast<const uint2*>(xin + (size_t)col1 * EMB + c4);
    uint2 r2 = *reinterpret_cast<const uint2*>(xin + (size_t)col2 * EMB + c4);
    uint2 r3 = *reinterpret_cast<const uint2*>(xin + (size_t)col3 * EMB + c4);
    a0 += w0 * bf2f(r0.x & 0xffff) + w1 * bf2f(r1.x & 0xffff) + w2 * bf2f(r2.x & 0xffff) + w3 * bf2f(r3.x & 0xffff);
    a1 += w0 * bf2f(r0.x >> 16)    + w1 * bf2f(r1.x >> 16)    + w2 * bf2f(r2.x >> 16)    + w3 * bf2f(r3.x >> 16);
    a2 += w0 * bf2f(r0.y & 0xffff) + w1 * bf2f(r1.y & 0xffff) + w2 * bf2f(r2.y & 0xffff) + w3 * bf2f(r3.y & 0xffff);
    a3 += w0 * bf2f(r0.y >> 16)    + w1 * bf2f(r1.y >> 16)    + w2 * bf2f(r2.y >> 16)    + w3 * bf2f(r3.y >> 16);
  }
  for (; s < e1; ++s) {
    int col = csr_col[s];
    float wv = csr_adj[s];
    uint2 r0 = *reinterpret_cast<const uint2*>(xin + (size_t)col * EMB + c4);
    a0 += wv * bf2f(r0.x & 0xffff);
    a1 += wv * bf2f(r0.x >> 16);
    a2 += wv * bf2f(r0.y & 0xffff);
    a3 += wv * bf2f(r0.y >> 16);
  }
  ushort4 o;
  o.x = f2bf(a0); o.y = f2bf(a1); o.z = f2bf(a2); o.w = f2bf(a3);
  *reinterpret_cast<ushort4*>(sout + (size_t)n * EMB + c4) = o;
}

// MFMA fused layer tail with double-buffered B staged in LDS via
// global_load_lds (all 4 waves share each k-step's 16KB of B).
__global__ __launch_bounds__(256) void k_fused(
    u16* __restrict__ h_bf,
    const u16* __restrict__ s1, const u16* __restrict__ s2, const u16* __restrict__ s3,
    const u16* __restrict__ wqF, const float* __restrict__ bq,
    const u16* __restrict__ MTF, const float* __restrict__ cvec, const float* __restrict__ kss,
    const u16* __restrict__ fcwF, const float* __restrict__ fcb,
    const float* __restrict__ lg, const float* __restrict__ lb) {
  __shared__ __align__(16) u16 aL[32 * 64 * 8];  // 32 KB A tile
  __shared__ __align__(16) u16 qL[16 * 64 * 8];  // 16 KB q half
  __shared__ __align__(16) u16 bL[2][16 * 512];  // 2 x 16 KB B k-step buffers
  int tid = threadIdx.x;
  int lane = tid & 63, w = tid >> 6;
  int g = lane >> 4, s = lane & 15;
  int n0 = blockIdx.x * 64;
  int wrow = w * 16;

  // prologue: stage h tile + first B k-step, one drain
  stage_rows(h_bf, aL, n0, w, lane);
  stage16(bsrc(0, wqF, MTF, fcwF), bL[0], w, lane);
  __syncthreads();

  // residual init from staged h
  f32x4 zac[16];
#pragma unroll
  for (int c = 0; c < 16; ++c) {
    int col = c * 16 + s;
#pragma unroll
    for (int r = 0; r < 4; ++r)
      zac[c][r] = bf2f(aL[((col >> 3) * 64 + wrow + g * 4 + r) * 8 + (col & 7)]);
  }

  int p = 0, step = 0;

  // ---- attention ----
  for (int hd = 0; hd < NH; ++hd) {
    f32x4 qa[16] = {};
#pragma unroll
    for (int kq = 0; kq < 8; ++kq) {
      stage16(bsrc(step + 1, wqF, MTF, fcwF), bL[p ^ 1], w, lane);
      short8 a = ld8(&aL[((kq * 4 + g) * 64 + wrow + s) * 8]);
#pragma unroll
      for (int c = 0; c < 16; ++c) {
        short8 b = ld8(&bL[p][c * 512 + lane * 8]);
        qa[c] = MFMA16(a, b, qa[c]);
      }
      __syncthreads();
      p ^= 1; ++step;
    }
    float nr[4] = {0.f, 0.f, 0.f, 0.f};
    float dp[4] = {0.f, 0.f, 0.f, 0.f};
#pragma unroll
    for (int c = 0; c < 16; ++c) {
      float bv = bq[hd * 256 + c * 16 + s];
      float kv = kss[hd * 256 + c * 16 + s];
#pragma unroll
      for (int r = 0; r < 4; ++r) {
        qa[c][r] += bv;
        nr[r] += qa[c][r] * qa[c][r];
        dp[r] += qa[c][r] * kv;
      }
    }
#pragma unroll
    for (int r = 0; r < 4; ++r) {
      nr[r] += __shfl_xor(nr[r], 1, 64);
      nr[r] += __shfl_xor(nr[r], 2, 64);
      nr[r] += __shfl_xor(nr[r], 4, 64);
      nr[r] += __shfl_xor(nr[r], 8, 64);
      dp[r] += __shfl_xor(dp[r], 1, 64);
      dp[r] += __shfl_xor(dp[r], 2, 64);
      dp[r] += __shfl_xor(dp[r], 4, 64);
      dp[r] += __shfl_xor(dp[r], 8, 64);
    }
    float sc[4], rdv[4];
#pragma unroll
    for (int r = 0; r < 4; ++r) {
      int row = n0 + wrow + g * 4 + r;
      float rn = (row < NN && nr[r] > 0.f) ? rsqrtf(nr[r]) : 0.f;
      rdv[r] = 1.f / (dp[r] * rn + (float)NN);
      sc[r] = rn * rdv[r];
    }
    // PV in two m-halves (qL holds 128 m at a time)
#pragma unroll
    for (int hh = 0; hh < 2; ++hh) {
      // previous reads of qL completed at last k-step's barrier
#pragma unroll
      for (int c = hh * 8; c < hh * 8 + 8; ++c) {
        int mh = (c - hh * 8) * 16 + s;
#pragma unroll
        for (int r = 0; r < 4; ++r)
          qL[((mh >> 3) * 64 + wrow + g * 4 + r) * 8 + (mh & 7)] = f2bf(qa[c][r] * sc[r]);
      }
      __syncthreads(); // qL visible
#pragma unroll
      for (int k4 = 0; k4 < 4; ++k4) {
        stage16(bsrc(step + 1, wqF, MTF, fcwF), bL[p ^ 1], w, lane);
        short8 a = ld8(&qL[((k4 * 4 + g) * 64 + wrow + s) * 8]);
#pragma unroll
        for (int c = 0; c < 16; ++c) {
          short8 b = ld8(&bL[p][c * 512 + lane * 8]);
          zac[c] = MFMA16(a, b, zac[c]);
        }
        __syncthreads();
        p ^= 1; ++step;
      }
    }
#pragma unroll
    for (int c = 0; c < 16; ++c) {
      float cv = cvec[hd * 256 + c * 16 + s];
#pragma unroll
      for (int r = 0; r < 4; ++r) zac[c][r] += cv * rdv[r];
    }
  }

  // ---- x2 = [h|s1|s2|s3] @ fcw[1024:2048] ----
  for (int sg = 0; sg < 4; ++sg) {
    if (sg > 0) {
      const u16* sp = (sg == 1) ? s1 : (sg == 2) ? s2 : s3;
      // all reads of aL done at last k-step's barrier
      stage_rows(sp, aL, n0, w, lane);
      __syncthreads(); // aL visible
    }
#pragma unroll
    for (int kq = 0; kq < 8; ++kq) {
      stage16(bsrc(step + 1, wqF, MTF, fcwF), bL[p ^ 1], w, lane);
      short8 a = ld8(&aL[((kq * 4 + g) * 64 + wrow + s) * 8]);
#pragma unroll
      for (int c = 0; c < 16; ++c) {
        short8 b = ld8(&bL[p][c * 512 + lane * 8]);
        zac[c] = MFMA16(a, b, zac[c]);
      }
      __syncthreads();
      p ^= 1; ++step;
    }
  }

  // ---- epilogue: + fc_b, LN, relu, store h_bf ----
  float sm[4] = {0.f, 0.f, 0.f, 0.f}, sq[4] = {0.f, 0.f, 0.f, 0.f};
#pragma unroll
  for (int c = 0; c < 16; ++c) {
    int col = c * 16 + s;
    float fb = fcb[col];
#pragma unroll
    for (int r = 0; r < 4; ++r) {
      float v = zac[c][r] + fb;
      zac[c][r] = v;
      sm[r] += v;
      sq[r] += v * v;
    }
  }
#pragma unroll
  for (int r = 0; r < 4; ++r) {
    sm[r] += __shfl_xor(sm[r], 1, 64);
    sm[r] += __shfl_xor(sm[r], 2, 64);
    sm[r] += __shfl_xor(sm[r], 4, 64);
    sm[r] += __shfl_xor(sm[r], 8, 64);
    sq[r] += __shfl_xor(sq[r], 1, 64);
    sq[r] += __shfl_xor(sq[r], 2, 64);
    sq[r] += __shfl_xor(sq[r], 4, 64);
    sq[r] += __shfl_xor(sq[r], 8, 64);
  }
  float mu[4], rs[4];
#pragma unroll
  for (int r = 0; r < 4; ++r) {
    mu[r] = sm[r] * (1.f / 256.f);
    float var = sq[r] * (1.f / 256.f) - mu[r] * mu[r];
    rs[r] = rsqrtf(var + 1e-5f);
  }
#pragma unroll
  for (int c = 0; c < 16; ++c) {
    int col = c * 16 + s;
    float gg = lg[col], bb = lb[col];
#pragma unroll
    for (int r = 0; r < 4; ++r) {
      int row = n0 + wrow + g * 4 + r;
      if (row < NN) {
        float o = fmaxf(0.f, (zac[c][r] - mu[r]) * rs[r] * gg + bb);
        h_bf[(size_t)row * EMB + col] = f2bf(o);
      }
    }
  }
}

// ---------------- pooling / output ----------------

__global__ void k_pool(const u16* __restrict__ h_bf, const int* __restrict__ batch,
                       float* __restrict__ pooled) {
  int t = threadIdx.x; // col
  int n0 = blockIdx.x * 64;
  if (n0 >= NN) return;
  int nend = n0 + 64;
  if (nend > NN) nend = NN;
  float run = 0.f;
  int cur = batch[n0];
  for (int n = n0; n < nend; ++n) {
    int b = batch[n];
    if (b != cur) {
      atomicAdd(&pooled[(size_t)cur * EMB + t], run);
      run = 0.f;
      cur = b;
    }
    run += bf2f(h_bf[(size_t)n * EMB + t]);
  }
  atomicAdd(&pooled[(size_t)cur * EMB + t], run);
}

__global__ void k_out(const float* __restrict__ pooled, const float* __restrict__ gcnt,
                      const float* __restrict__ ow, const float* __restrict__ ob,
                      float* __restrict__ out) {
  __shared__ float prow[EMB];
  int g = blockIdx.x, t = threadIdx.x;
  float rc = 1.f / fmaxf(gcnt[g], 1.f);
  for (int i = t; i < EMB; i += TASKS) prow[i] = pooled[(size_t)g * EMB + i] * rc;
  __syncthreads();
  float acc = ob[t];
#pragma unroll 4
  for (int d = 0; d < EMB; ++d) acc += prow[d] * ow[d * TASKS + t];
  out[(size_t)g * TASKS + t] = acc;
}

// ---------------- launch ----------------

extern "C" void kernel_launch(void* const* d_in, const int* in_sizes, int n_in,
                              void* d_out, int out_size, void* d_ws, size_t ws_size,
                              hipStream_t stream) {
  const int* x = (const int*)d_in[0];
  const int* eidx = (const int*)d_in[1];
  const int* eattr = (const int*)d_in[2];
  const int* batch = (const int*)d_in[3];
  const float* aemb = (const float*)d_in[4];
  const float* bemb = (const float*)d_in[5];
  const float* wq = (const float*)d_in[6];
  const float* bq = (const float*)d_in[7];
  const float* wk = (const float*)d_in[8];
  const float* bk = (const float*)d_in[9];
  const float* fcw = (const float*)d_in[10];
  const float* fcb = (const float*)d_in[11];
  const float* lg = (const float*)d_in[12];
  const float* lb = (const float*)d_in[13];
  const float* ow = (const float*)d_in[14];
  const float* ob = (const float*)d_in[15];
  float* out = (float*)d_out;

  size_t off = 0;
  auto alloc = [&](size_t bytes) -> void* {
    void* r = (char*)d_ws + off;
    off += (bytes + 255) & ~(size_t)255;
    return r;
  };
  u16* h_bf = (u16*)alloc((size_t)NN * EMB * 2);        // 25.6 MB
  u16* region = (u16*)alloc((size_t)HE * NS * 2);       // 102.5 MB (knF | msg,s1,s2,s3)
  u16* knF = region;
  u16* msg = region;
  u16* s1 = region + (size_t)NN * EMB;
  u16* s2 = region + (size_t)2 * NN * EMB;
  u16* s3 = region + (size_t)3 * NN * EMB;
  u16* hF = (u16*)alloc((size_t)EMB * NS * 2);          // 25.6 MB
  float* kvs = (float*)alloc((size_t)HE * EMB * 4);     // 1 MB
  float* Mm = (float*)alloc((size_t)HE * EMB * 4);      // 1 MB
  u16* MTF = (u16*)alloc((size_t)HE * EMB * 2);         // 0.5 MB
  u16* wqF = (u16*)alloc((size_t)NL * HE * EMB * 2);    // 2.1 MB
  u16* wkF = (u16*)alloc((size_t)NL * HE * EMB * 2);    // 2.1 MB
  u16* fcwF = (u16*)alloc((size_t)NL * 2048 * EMB * 2); // 4.2 MB
  float* cvec = (float*)alloc((size_t)NH * EMB * 4);
  float* ksh = (float*)alloc((size_t)(HE + EMB) * 4); // ks_sum | h_sum
  float* ks_sum = ksh;
  float* h_sum = ksh + HE;
  float* dinv_i = (float*)alloc((size_t)NN * 4);
  float* dinv_j = (float*)alloc((size_t)NN * 4);
  int* deg_i = (int*)alloc((size_t)NN * 4);
  int* deg_j = (int*)alloc((size_t)NN * 4);
  int* offs = (int*)alloc((size_t)(NN + 1) * 4);
  int* cursor = (int*)alloc((size_t)NN * 4);
  int* csr_col = (int*)alloc((size_t)NE * 4);
  float* csr_adj = (float*)alloc((size_t)NE * 4);
  int* csr_pack = (int*)alloc((size_t)NE * 4);
  float* pooled = (float*)alloc((size_t)NG * EMB * 4);
  float* gcnt = (float*)alloc((size_t)NG * 4);

  if (off > ws_size) {
    k_fill<<<(out_size + 255) / 256, 256, 0, stream>>>(out, out_size, 1048576.f);
    return;
  }

  const int* row = eidx;
  const int* colp = eidx + NE;

  k_zero<<<(NN + 255) / 256, 256, 0, stream>>>((u32*)deg_i, NN);
  k_zero<<<(NN + 255) / 256, 256, 0, stream>>>((u32*)deg_j, NN);
  k_zero<<<(NN + 255) / 256, 256, 0, stream>>>((u32*)cursor, NN);
  k_zero<<<(NG + 255) / 256, 256, 0, stream>>>((u32*)gcnt, NG);
  k_zero<<<(NG * EMB + 255) / 256, 256, 0, stream>>>((u32*)pooled, NG * EMB);

  // one-time fragment-major weight packs
  k_frag<<<dim3(8, 64, NL), 64, 0, stream>>>(wq, wqF, 1024, 64, 0,
                                             (long)EMB * HE, (long)HE * EMB);
  k_frag<<<dim3(8, 64, NL), 64, 0, stream>>>(wk, wkF, 1024, 64, 0,
                                             (long)EMB * HE, (long)HE * EMB);
  k_frag<<<dim3(64, 16, NL), 64, 0, stream>>>(fcw, fcwF, 256, 16, 0,
                                              (long)2048 * EMB, (long)2048 * EMB);

  k_atom<<<NN, EMB, 0, stream>>>(x, aemb, h_bf);
  k_deg<<<NE / 256, 256, 0, stream>>>(row, colp, deg_i, deg_j);
  k_dinv<<<(NN + 255) / 256, 256, 0, stream>>>(deg_i, deg_j, dinv_i, dinv_j);
  k_scan<<<1, 1024, 0, stream>>>(deg_i, offs);
  k_csr<<<NE / 256, 256, 0, stream>>>(row, colp, eattr, dinv_i, dinv_j, offs, cursor,
                                      csr_col, csr_adj, csr_pack);
  k_gcnt<<<(NN + 255) / 256, 256, 0, stream>>>(batch, gcnt);

  for (int l = 0; l < NL; ++l) {
    const float* fcw_l = fcw + (size_t)l * 2048 * EMB;
    k_zero<<<(HE + EMB + 255) / 256, 256, 0, stream>>>((u32*)ksh, HE + EMB);
    k_zero<<<(HE * EMB + 255) / 256, 256, 0, stream>>>((u32*)kvs, HE * EMB);
    // --- phase 1: region holds knF ---
    k_projk<<<dim3(GB64, NH), 256, 0, stream>>>(h_bf, wkF + (size_t)l * HE * EMB,
                                                bk + (size_t)l * HE, knF, ks_sum, h_sum);
    k_htrf<<<dim3(GB64, 4), 256, 0, stream>>>(h_bf, hF);
    k_kvs<<<dim3(16, KVS_SL), 256, 0, stream>>>(knF, hF, kvs);
    k_mpre<<<HE, 256, 0, stream>>>(kvs, fcw_l, Mm);
    k_frag<<<dim3(8, 16, NH), 64, 0, stream>>>(Mm, MTF, 256, 64, 16,
                                               (long)EMB * EMB, 0);
    k_cvec<<<NH, 256, 0, stream>>>(h_sum, fcw_l, cvec);
    // --- phase 2: knF dead; region becomes msg/s1/s2/s3 ---
    k_message<<<NN / 16, 256, 0, stream>>>(bemb + (size_t)l * 3 * 10 * EMB, offs, csr_adj,
                                           csr_pack, msg);
    k_spmm<<<NN / 4, 256, 0, stream>>>(h_bf, msg, offs, csr_col, csr_adj, s1);
    k_spmm<<<NN / 4, 256, 0, stream>>>(s1, msg, offs, csr_col, csr_adj, s2);
    k_spmm<<<NN / 4, 256, 0, stream>>>(s2, msg, offs, csr_col, csr_adj, s3);
    k_fused<<<GB64, 256, 0, stream>>>(h_bf, s1, s2, s3, wqF + (size_t)l * HE * EMB,
                                      bq + (size_t)l * HE, MTF, cvec, ks_sum,
                                      fcwF + (size_t)l * 2048 * EMB, fcb + (size_t)l * EMB,
                                      lg + (size_t)l * EMB, lb + (size_t)l * EMB);
  }
  k_pool<<<(NN + 63) / 64, 256, 0, stream>>>(h_bf, batch, pooled);
  k_out<<<NG, TASKS, 0, stream>>>(pooled, gcnt, ow, ob, out);
}

// Round 10
// 3201.233 us; speedup vs baseline: 2.2938x; 1.2650x over previous
//
#include <hip/hip_runtime.h>

#define DEV __device__ __forceinline__

constexpr int NN = 50000;
constexpr int NE = 800000;
constexpr int NG = 1024;
constexpr int EMB = 256;
constexpr int NH = 4;
constexpr int HE = 1024;   // NH*EMB
constexpr int NL = 4;
constexpr int TASKS = 128;
constexpr int NS = 50048;            // padded nodes (multiple of 128)
constexpr int NCH = NS / 32;         // 1564 K-chunks for kvs
constexpr int KVS_SL = 64;           // kvs n-slices (TLP)
constexpr int GB64 = NS / 64;        // 782
constexpr int GB128 = NS / 128;      // 391

using u16 = unsigned short;
using u32 = unsigned int;

typedef __attribute__((ext_vector_type(8))) short short8;
typedef __attribute__((ext_vector_type(4))) float f32x4;

#define MFMA16(a8, b8, c4) __builtin_amdgcn_mfma_f32_16x16x32_bf16(a8, b8, c4, 0, 0, 0)

DEV u16 f2bf(float f) {
  u32 u = __float_as_uint(f);
  u32 r = (u + 0x7FFFu + ((u >> 16) & 1u)) >> 16;
  return (u16)r;
}
DEV float bf2f(u16 s) { return __uint_as_float(((u32)s) << 16); }
DEV short8 ld8(const u16* p) { return *reinterpret_cast<const short8*>(p); }

// async global->LDS, 16B per lane; LDS dst is wave-uniform base + lane*16
DEV void gld16(const u16* g, u16* l) {
  __builtin_amdgcn_global_load_lds(
      (const __attribute__((address_space(1))) void*)g,
      (__attribute__((address_space(3))) void*)l, 16, 0, 0);
}

// stage one k-step of B (16 fragments x 1KB) with 8 waves: wave w -> frags 2w,2w+1
DEV void stage16_8(const u16* __restrict__ src, u16* dst, int w, int lane) {
#pragma unroll
  for (int i = 0; i < 2; ++i) {
    int f = w * 2 + i;
    gld16(src + (size_t)f * 512 + lane * 8, dst + f * 512);
  }
}

// stage a 128-row x 256-col bf16 A tile into aL layout [(k>>3)*128 + row][8]
// UNGUARDED: pad rows read in-ws garbage; row-local through MFMA, never stored.
DEV void stage_rows128(const u16* __restrict__ src, u16* dst, int n0, int w, int lane) {
#pragma unroll
  for (int i = 0; i < 4; ++i) {
    int kc = w * 4 + i;
#pragma unroll
    for (int rh = 0; rh < 2; ++rh)
      gld16(src + (size_t)(n0 + rh * 64 + lane) * EMB + kc * 8,
            dst + (kc * 128 + rh * 64) * 8);
  }
}

// B-fragment source for virtual k-step of k_fused (96 steps)
DEV const u16* bsrc(int step, const u16* wqF, const u16* MTF, const u16* fcwF) {
  if (step > 95) step = 95;
  if (step < 64) {
    int hd = step >> 4, t = step & 15;
    if (t < 8) return wqF + ((size_t)(t * 64 + hd * 16)) * 512;
    return MTF + ((size_t)((t - 8) * 64 + hd * 16)) * 512;
  }
  return fcwF + ((size_t)(32 + (step - 64)) * 16) * 512;
}

// ---------------- utility ----------------

__global__ void k_zero(u32* __restrict__ p, int n) {
  int i = blockIdx.x * 256 + threadIdx.x;
  if (i < n) p[i] = 0u;
}

__global__ void k_fill(float* __restrict__ p, int n, float v) {
  int i = blockIdx.x * 256 + threadIdx.x;
  if (i < n) p[i] = v;
}

// Pack a [K][R] f32 matrix into MFMA B-fragment-major bf16.
__global__ void k_frag(const float* __restrict__ in, u16* __restrict__ outp,
                       int R, int rqTot, int rqStep, long inStride, long outStride) {
  int nc = blockIdx.x, rq = blockIdx.y, b = blockIdx.z;
  int l = threadIdx.x & 63;
  int g = l >> 4, s = l & 15;
  const float* ip = in + (size_t)b * inStride + (size_t)(nc * 32 + g * 8) * R + rq * 16 + s;
  short8 v;
#pragma unroll
  for (int j = 0; j < 8; ++j) v[j] = (short)f2bf(ip[(size_t)j * R]);
  u16* op = outp + (size_t)b * outStride +
            ((size_t)(nc * rqTot + b * rqStep + rq) * 64 + l) * 8;
  *reinterpret_cast<short8*>(op) = v;
}

// h -> fragment-major hF (K = node dim, rows = d).  Zero-padded to NS.
__global__ void k_htrf(const u16* __restrict__ h_bf, u16* __restrict__ hF) {
  __shared__ u16 t[64][72];
  int tid = threadIdx.x;
  int n0 = blockIdx.x * 64, d0 = blockIdx.y * 64;
#pragma unroll
  for (int rr = 0; rr < 2; ++rr) {
    int nl = rr * 32 + (tid >> 3);
    int dd = (tid & 7) * 8;
    uint4 v = {0u, 0u, 0u, 0u};
    int n = n0 + nl;
    if (n < NN) v = *reinterpret_cast<const uint4*>(h_bf + (size_t)n * EMB + d0 + dd);
    *reinterpret_cast<uint4*>(&t[nl][dd]) = v;
  }
  __syncthreads();
#pragma unroll
  for (int k = 0; k < 2; ++k) {
    int u = tid + 256 * k;          // 512 output ushort8 units
    int nchL = u >> 8;              // 0..1
    int rqL = (u >> 6) & 3;         // 0..3
    int l = u & 63;
    int g = l >> 4, s = l & 15;
    short8 v;
#pragma unroll
    for (int j = 0; j < 8; ++j) v[j] = (short)t[nchL * 32 + g * 8 + j][rqL * 16 + s];
    *reinterpret_cast<short8*>(
        &hF[(((size_t)((n0 >> 5) + nchL) * 16 + (d0 >> 4) + rqL) * 64 + l) * 8]) = v;
  }
}

// ---------------- setup kernels ----------------

__global__ void k_atom(const int* __restrict__ x, const float* __restrict__ aemb,
                       u16* __restrict__ h_bf) {
  int n = blockIdx.x, d = threadIdx.x;
  const int* xr = x + n * 9;
  float acc = 0.f;
#pragma unroll
  for (int f = 0; f < 9; ++f) acc += aemb[(f * 100 + xr[f]) * EMB + d];
  h_bf[(size_t)n * EMB + d] = f2bf(acc);
}

__global__ void k_deg(const int* __restrict__ row, const int* __restrict__ col,
                      int* __restrict__ deg_i, int* __restrict__ deg_j) {
  int e = blockIdx.x * 256 + threadIdx.x;
  if (e < NE) {
    atomicAdd(&deg_i[row[e]], 1);
    atomicAdd(&deg_j[col[e]], 1);
  }
}

__global__ void k_dinv(const int* __restrict__ deg_i, const int* __restrict__ deg_j,
                       float* __restrict__ di, float* __restrict__ dj) {
  int n = blockIdx.x * 256 + threadIdx.x;
  if (n < NN) {
    di[n] = deg_i[n] > 0 ? rsqrtf((float)deg_i[n]) : 0.f;
    dj[n] = deg_j[n] > 0 ? rsqrtf((float)deg_j[n]) : 0.f;
  }
}

__global__ void k_scan(const int* __restrict__ deg, int* __restrict__ offs) {
  __shared__ int tot[1024];
  int t = threadIdx.x;
  constexpr int PER = (NN + 1023) / 1024; // 49
  int lo = t * PER, hi = lo + PER;
  if (hi > NN) hi = NN;
  int s = 0;
  for (int i = lo; i < hi; ++i) s += deg[i];
  tot[t] = s;
  __syncthreads();
  for (int off = 1; off < 1024; off <<= 1) {
    int v = (t >= off) ? tot[t - off] : 0;
    __syncthreads();
    tot[t] += v;
    __syncthreads();
  }
  int run = (t == 0) ? 0 : tot[t - 1];
  for (int i = lo; i < hi; ++i) { offs[i] = run; run += deg[i]; }
  if (t == 0) offs[NN] = NE;
}

__global__ void k_csr(const int* __restrict__ row, const int* __restrict__ col,
                      const int* __restrict__ eattr, const float* __restrict__ di,
                      const float* __restrict__ dj, const int* __restrict__ offs,
                      int* __restrict__ cursor, int* __restrict__ csr_col,
                      float* __restrict__ csr_adj, int* __restrict__ csr_pack) {
  int e = blockIdx.x * 256 + threadIdx.x;
  if (e >= NE) return;
  int r = row[e], c = col[e];
  int slot = offs[r] + atomicAdd(&cursor[r], 1);
  csr_col[slot] = c;
  csr_adj[slot] = di[r] * dj[c];
  csr_pack[slot] = eattr[e * 3] | (eattr[e * 3 + 1] << 8) | (eattr[e * 3 + 2] << 16);
}

__global__ void k_gcnt(const int* __restrict__ batch, float* __restrict__ gcnt) {
  int n = blockIdx.x * 256 + threadIdx.x;
  if (n < NN) atomicAdd(&gcnt[batch[n]], 1.f);
}

// ---------------- per-layer kernels ----------------

__global__ void k_message(const float* __restrict__ bond, const int* __restrict__ offs,
                          const float* __restrict__ csr_adj, const int* __restrict__ csr_pack,
                          u16* __restrict__ msg) {
  __shared__ float tab[3 * 10 * EMB]; // 30 KB
  int tid = threadIdx.x;
  for (int i = tid; i < 3 * 10 * EMB; i += 256) tab[i] = bond[i];
  __syncthreads();
  int n0 = blockIdx.x * 16;
  for (int nn = 0; nn < 16; ++nn) {
    int n = n0 + nn;
    int e0 = offs[n], e1 = offs[n + 1];
    float acc = 0.f;
    for (int s = e0; s < e1; ++s) {
      float a = csr_adj[s];
      int pk = csr_pack[s];
      int a0 = pk & 255, a1 = (pk >> 8) & 255, a2 = (pk >> 16) & 255;
      acc += a * (tab[a0 * EMB + tid] + tab[(10 + a1) * EMB + tid] + tab[(20 + a2) * EMB + tid]);
    }
    msg[(size_t)n * EMB + tid] = f2bf(acc);
  }
}

// MFMA k-projection, ONE HEAD per block. k = h@Wk + bk, row-normalize,
// write knF (fragment-major), accumulate ks_sum (+h_sum on hd 0).
__global__ __launch_bounds__(256) void k_projk(
    const u16* __restrict__ h_bf, const u16* __restrict__ wkF, const float* __restrict__ bk,
    u16* __restrict__ knF, float* __restrict__ ks_sum, float* __restrict__ h_sum) {
  __shared__ __align__(16) u16 aL[32 * 64 * 8]; // 32 KB
  __shared__ float red[4][EMB];                 // 4 KB
  int tid = threadIdx.x;
  int lane = tid & 63, w = tid >> 6;
  int g = lane >> 4, s = lane & 15;
  int n0 = blockIdx.x * 64;
  int hd = blockIdx.y;
  int wrow = w * 16;
  { // stage A tile from h_bf (guarded: knF pads must be exactly zero)
    int r = tid & 63, kq = tid >> 6;
#pragma unroll
    for (int ii = 0; ii < 8; ++ii) {
      int k = kq * 64 + ii * 8;
      int row = n0 + r;
      uint4 v = {0u, 0u, 0u, 0u};
      if (row < NN) v = *reinterpret_cast<const uint4*>(h_bf + (size_t)row * EMB + k);
      *reinterpret_cast<uint4*>(&aL[((k >> 3) * 64 + r) * 8]) = v;
    }
  }
  __syncthreads();
  if (hd == 0) { // h_sum once per tile
    float ss = 0.f;
#pragma unroll 8
    for (int r = 0; r < 64; ++r) ss += bf2f(aL[((tid >> 3) * 64 + r) * 8 + (tid & 7)]);
    atomicAdd(&h_sum[tid], ss);
  }
  f32x4 ka[16] = {};
#pragma unroll
  for (int k0 = 0; k0 < 256; k0 += 32) {
    short8 a = ld8(&aL[(((k0 >> 3) + g) * 64 + wrow + s) * 8]);
#pragma unroll
    for (int c = 0; c < 16; ++c) {
      short8 b = ld8(&wkF[(((size_t)(k0 >> 5) * 64 + hd * 16 + c) * 64 + lane) * 8]);
      ka[c] = MFMA16(a, b, ka[c]);
    }
  }
  float nr[4] = {0.f, 0.f, 0.f, 0.f};
#pragma unroll
  for (int c = 0; c < 16; ++c) {
    float bv = bk[hd * 256 + c * 16 + s];
#pragma unroll
    for (int r = 0; r < 4; ++r) {
      ka[c][r] += bv;
      nr[r] += ka[c][r] * ka[c][r];
    }
  }
#pragma unroll
  for (int r = 0; r < 4; ++r) {
    nr[r] += __shfl_xor(nr[r], 1, 64);
    nr[r] += __shfl_xor(nr[r], 2, 64);
    nr[r] += __shfl_xor(nr[r], 4, 64);
    nr[r] += __shfl_xor(nr[r], 8, 64);
  }
  float rn[4];
#pragma unroll
  for (int r = 0; r < 4; ++r) {
    int row = n0 + wrow + g * 4 + r;
    rn[r] = (row < NN && nr[r] > 0.f) ? rsqrtf(nr[r]) : 0.f; // 0 for pad rows
  }
  int nn = wrow + g * 4;
  int nch = (n0 + nn) >> 5;
  int gc = (nn >> 3) & 3;
  int jb = nn & 7; // 0 or 4
  float cs[16];
#pragma unroll
  for (int c = 0; c < 16; ++c) {
    float v0 = ka[c][0] * rn[0], v1 = ka[c][1] * rn[1];
    float v2 = ka[c][2] * rn[2], v3 = ka[c][3] * rn[3];
    cs[c] = v0 + v1 + v2 + v3;
    ushort4 pk;
    pk.x = f2bf(v0); pk.y = f2bf(v1); pk.z = f2bf(v2); pk.w = f2bf(v3);
    *reinterpret_cast<ushort4*>(
        &knF[(((size_t)nch * 64 + hd * 16 + c) * 64 + gc * 16 + s) * 8 + jb]) = pk;
  }
#pragma unroll
  for (int c = 0; c < 16; ++c) {
    cs[c] += __shfl_xor(cs[c], 16, 64);
    cs[c] += __shfl_xor(cs[c], 32, 64);
  }
  if (g == 0) {
#pragma unroll
    for (int c = 0; c < 16; ++c) red[w][c * 16 + s] = cs[c];
  }
  __syncthreads();
  float tot = red[0][tid] + red[1][tid] + red[2][tid] + red[3][tid];
  atomicAdd(&ks_sum[hd * 256 + tid], tot);
}

// MFMA kvs: kvs[j][d] += sum_n knF[j][n] * hF[d][n]; 128 j per block.
__global__ __launch_bounds__(256) void k_kvs(const u16* __restrict__ knF,
                                             const u16* __restrict__ hF,
                                             float* __restrict__ kvs) {
  int tid = threadIdx.x;
  int lane = tid & 63, w = tid >> 6;
  int s = lane & 15, g = lane >> 4;
  int j0 = blockIdx.x * 128;
  int sl = blockIdx.y;
  f32x4 acc[8][4] = {}; // [jf][df]
  for (int ch = sl; ch < NCH; ch += KVS_SL) {
    short8 bfr[4];
#pragma unroll
    for (int df = 0; df < 4; ++df)
      bfr[df] = ld8(&hF[(((size_t)ch * 16 + w * 4 + df) * 64 + lane) * 8]);
#pragma unroll
    for (int jf = 0; jf < 8; ++jf) {
      short8 a = ld8(&knF[(((size_t)ch * 64 + (j0 >> 4) + jf) * 64 + lane) * 8]);
#pragma unroll
      for (int df = 0; df < 4; ++df) acc[jf][df] = MFMA16(a, bfr[df], acc[jf][df]);
    }
  }
#pragma unroll
  for (int jf = 0; jf < 8; ++jf)
#pragma unroll
    for (int df = 0; df < 4; ++df)
#pragma unroll
      for (int r = 0; r < 4; ++r)
        atomicAdd(&kvs[(size_t)(j0 + jf * 16 + g * 4 + r) * EMB + w * 64 + df * 16 + s],
                  acc[jf][df][r]);
}

// M[hd*256+m][o] = sum_d kvs[hd*256+m][d] * fcw[(hd*256+d)*256+o]  (fp32)
__global__ void k_mpre(const float* __restrict__ kvs, const float* __restrict__ fcw,
                       float* __restrict__ M) {
  __shared__ float arow[EMB];
  int bid = blockIdx.x; // hd*256+m
  int hd = bid >> 8;
  int t = threadIdx.x;
  arow[t] = kvs[(size_t)bid * EMB + t];
  __syncthreads();
  float acc = 0.f;
  const float* wp = fcw + (size_t)(hd * 256) * EMB + t;
#pragma unroll 4
  for (int d = 0; d < EMB; ++d) acc += arow[d] * wp[(size_t)d * EMB];
  M[(size_t)bid * EMB + t] = acc;
}

__global__ void k_cvec(const float* __restrict__ h_sum, const float* __restrict__ fcw,
                       float* __restrict__ c) {
  __shared__ float arow[EMB];
  int hd = blockIdx.x;
  int t = threadIdx.x;
  arow[t] = h_sum[t];
  __syncthreads();
  float acc = 0.f;
  const float* wp = fcw + (size_t)(hd * 256) * EMB + t;
#pragma unroll 4
  for (int d = 0; d < EMB; ++d) acc += arow[d] * wp[(size_t)d * EMB];
  c[hd * EMB + t] = acc;
}

// SpMM: wave-per-node, lane owns 4 cols; bf16 in/out, 4-edge unroll.
__global__ __launch_bounds__(256) void k_spmm(
    const u16* __restrict__ xin, const u16* __restrict__ msg,
    const int* __restrict__ offs, const int* __restrict__ csr_col,
    const float* __restrict__ csr_adj, u16* __restrict__ sout) {
  int lane = threadIdx.x & 63, w = threadIdx.x >> 6;
  int n = blockIdx.x * 4 + w;
  if (n >= NN) return;
  int c4 = lane * 4;
  uint2 m = *reinterpret_cast<const uint2*>(msg + (size_t)n * EMB + c4);
  float a0 = bf2f(m.x & 0xffff), a1 = bf2f(m.x >> 16);
  float a2 = bf2f(m.y & 0xffff), a3 = bf2f(m.y >> 16);
  int e0 = offs[n], e1 = offs[n + 1];
  int s = e0;
  for (; s + 4 <= e1; s += 4) {
    int col0 = csr_col[s], col1 = csr_col[s + 1], col2 = csr_col[s + 2], col3 = csr_col[s + 3];
    float w0 = csr_adj[s], w1 = csr_adj[s + 1], w2 = csr_adj[s + 2], w3 = csr_adj[s + 3];
    uint2 r0 = *reinterpret_cast<const uint2*>(xin + (size_t)col0 * EMB + c4);
    uint2 r1 = *reinterpret_cast<const uint2*>(xin + (size_t)col1 * EMB + c4);
    uint2 r2 = *reinterpret_cast<const uint2*>(xin + (size_t)col2 * EMB + c4);
    uint2 r3 = *reinterpret_cast<const uint2*>(xin + (size_t)col3 * EMB + c4);
    a0 += w0 * bf2f(r0.x & 0xffff) + w1 * bf2f(r1.x & 0xffff) + w2 * bf2f(r2.x & 0xffff) + w3 * bf2f(r3.x & 0xffff);
    a1 += w0 * bf2f(r0.x >> 16)    + w1 * bf2f(r1.x >> 16)    + w2 * bf2f(r2.x >> 16)    + w3 * bf2f(r3.x >> 16);
    a2 += w0 * bf2f(r0.y & 0xffff) + w1 * bf2f(r1.y & 0xffff) + w2 * bf2f(r2.y & 0xffff) + w3 * bf2f(r3.y & 0xffff);
    a3 += w0 * bf2f(r0.y >> 16)    + w1 * bf2f(r1.y >> 16)    + w2 * bf2f(r2.y >> 16)    + w3 * bf2f(r3.y >> 16);
  }
  for (; s < e1; ++s) {
    int col = csr_col[s];
    float wv = csr_adj[s];
    uint2 r0 = *reinterpret_cast<const uint2*>(xin + (size_t)col * EMB + c4);
    a0 += wv * bf2f(r0.x & 0xffff);
    a1 += wv * bf2f(r0.x >> 16);
    a2 += wv * bf2f(r0.y & 0xffff);
    a3 += wv * bf2f(r0.y >> 16);
  }
  ushort4 o;
  o.x = f2bf(a0); o.y = f2bf(a1); o.z = f2bf(a2); o.w = f2bf(a3);
  *reinterpret_cast<ushort4*>(sout + (size_t)n * EMB + c4) = o;
}

// MFMA fused layer tail: TALL block — 8 waves, 128 rows, LDS-staged B
// double-buffered via global_load_lds (16KB B shared by 8 waves per step).
__global__ __launch_bounds__(512) void k_fused(
    u16* __restrict__ h_bf,
    const u16* __restrict__ s1, const u16* __restrict__ s2, const u16* __restrict__ s3,
    const u16* __restrict__ wqF, const float* __restrict__ bq,
    const u16* __restrict__ MTF, const float* __restrict__ cvec, const float* __restrict__ kss,
    const u16* __restrict__ fcwF, const float* __restrict__ fcb,
    const float* __restrict__ lg, const float* __restrict__ lb) {
  __shared__ __align__(16) u16 aL[32 * 128 * 8];  // 64 KB A tile (128 rows)
  __shared__ __align__(16) u16 qL[16 * 128 * 8];  // 32 KB q half (128 rows)
  __shared__ __align__(16) u16 bL[2][16 * 512];   // 2 x 16 KB B k-step buffers
  int tid = threadIdx.x;
  int lane = tid & 63, w = tid >> 6;          // w in 0..7
  int g = lane >> 4, s = lane & 15;
  int n0 = blockIdx.x * 128;
  int wrow = w * 16;

  // prologue: stage h tile + first B k-step, one drain
  stage_rows128(h_bf, aL, n0, w, lane);
  stage16_8(bsrc(0, wqF, MTF, fcwF), bL[0], w, lane);
  __syncthreads();

  // residual init from staged h
  f32x4 zac[16];
#pragma unroll
  for (int c = 0; c < 16; ++c) {
    int col = c * 16 + s;
#pragma unroll
    for (int r = 0; r < 4; ++r)
      zac[c][r] = bf2f(aL[((col >> 3) * 128 + wrow + g * 4 + r) * 8 + (col & 7)]);
  }

  int p = 0, step = 0;

  // ---- attention ----
  for (int hd = 0; hd < NH; ++hd) {
    f32x4 qa[16] = {};
#pragma unroll
    for (int kq = 0; kq < 8; ++kq) {
      stage16_8(bsrc(step + 1, wqF, MTF, fcwF), bL[p ^ 1], w, lane);
      short8 a = ld8(&aL[((kq * 4 + g) * 128 + wrow + s) * 8]);
#pragma unroll
      for (int c = 0; c < 16; ++c) {
        short8 b = ld8(&bL[p][c * 512 + lane * 8]);
        qa[c] = MFMA16(a, b, qa[c]);
      }
      __syncthreads();
      p ^= 1; ++step;
    }
    float nr[4] = {0.f, 0.f, 0.f, 0.f};
    float dp[4] = {0.f, 0.f, 0.f, 0.f};
#pragma unroll
    for (int c = 0; c < 16; ++c) {
      float bv = bq[hd * 256 + c * 16 + s];
      float kv = kss[hd * 256 + c * 16 + s];
#pragma unroll
      for (int r = 0; r < 4; ++r) {
        qa[c][r] += bv;
        nr[r] += qa[c][r] * qa[c][r];
        dp[r] += qa[c][r] * kv;
      }
    }
#pragma unroll
    for (int r = 0; r < 4; ++r) {
      nr[r] += __shfl_xor(nr[r], 1, 64);
      nr[r] += __shfl_xor(nr[r], 2, 64);
      nr[r] += __shfl_xor(nr[r], 4, 64);
      nr[r] += __shfl_xor(nr[r], 8, 64);
      dp[r] += __shfl_xor(dp[r], 1, 64);
      dp[r] += __shfl_xor(dp[r], 2, 64);
      dp[r] += __shfl_xor(dp[r], 4, 64);
      dp[r] += __shfl_xor(dp[r], 8, 64);
    }
    float sc[4], rdv[4];
#pragma unroll
    for (int r = 0; r < 4; ++r) {
      int row = n0 + wrow + g * 4 + r;
      float rn = (row < NN && nr[r] > 0.f) ? rsqrtf(nr[r]) : 0.f;
      rdv[r] = 1.f / (dp[r] * rn + (float)NN);
      sc[r] = rn * rdv[r];
    }
    // PV in two m-halves (qL holds 128 m at a time)
#pragma unroll
    for (int hh = 0; hh < 2; ++hh) {
      // previous reads of qL completed at last k-step's barrier
#pragma unroll
      for (int c = hh * 8; c < hh * 8 + 8; ++c) {
        int mh = (c - hh * 8) * 16 + s;
#pragma unroll
        for (int r = 0; r < 4; ++r)
          qL[((mh >> 3) * 128 + wrow + g * 4 + r) * 8 + (mh & 7)] = f2bf(qa[c][r] * sc[r]);
      }
      __syncthreads(); // qL visible
#pragma unroll
      for (int k4 = 0; k4 < 4; ++k4) {
        stage16_8(bsrc(step + 1, wqF, MTF, fcwF), bL[p ^ 1], w, lane);
        short8 a = ld8(&qL[((k4 * 4 + g) * 128 + wrow + s) * 8]);
#pragma unroll
        for (int c = 0; c < 16; ++c) {
          short8 b = ld8(&bL[p][c * 512 + lane * 8]);
          zac[c] = MFMA16(a, b, zac[c]);
        }
        __syncthreads();
        p ^= 1; ++step;
      }
    }
#pragma unroll
    for (int c = 0; c < 16; ++c) {
      float cv = cvec[hd * 256 + c * 16 + s];
#pragma unroll
      for (int r = 0; r < 4; ++r) zac[c][r] += cv * rdv[r];
    }
  }

  // ---- x2 = [h|s1|s2|s3] @ fcw[1024:2048] ----
  for (int sg = 0; sg < 4; ++sg) {
    if (sg > 0) {
      const u16* sp = (sg == 1) ? s1 : (sg == 2) ? s2 : s3;
      // all reads of aL done at last k-step's barrier
      stage_rows128(sp, aL, n0, w, lane);
      __syncthreads(); // aL visible
    }
#pragma unroll
    for (int kq = 0; kq < 8; ++kq) {
      stage16_8(bsrc(step + 1, wqF, MTF, fcwF), bL[p ^ 1], w, lane);
      short8 a = ld8(&aL[((kq * 4 + g) * 128 + wrow + s) * 8]);
#pragma unroll
      for (int c = 0; c < 16; ++c) {
        short8 b = ld8(&bL[p][c * 512 + lane * 8]);
        zac[c] = MFMA16(a, b, zac[c]);
      }
      __syncthreads();
      p ^= 1; ++step;
    }
  }

  // ---- epilogue: + fc_b, LN, relu, store h_bf ----
  float sm[4] = {0.f, 0.f, 0.f, 0.f}, sq[4] = {0.f, 0.f, 0.f, 0.f};
#pragma unroll
  for (int c = 0; c < 16; ++c) {
    int col = c * 16 + s;
    float fb = fcb[col];
#pragma unroll
    for (int r = 0; r < 4; ++r) {
      float v = zac[c][r] + fb;
      zac[c][r] = v;
      sm[r] += v;
      sq[r] += v * v;
    }
  }
#pragma unroll
  for (int r = 0; r < 4; ++r) {
    sm[r] += __shfl_xor(sm[r], 1, 64);
    sm[r] += __shfl_xor(sm[r], 2, 64);
    sm[r] += __shfl_xor(sm[r], 4, 64);
    sm[r] += __shfl_xor(sm[r], 8, 64);
    sq[r] += __shfl_xor(sq[r], 1, 64);
    sq[r] += __shfl_xor(sq[r], 2, 64);
    sq[r] += __shfl_xor(sq[r], 4, 64);
    sq[r] += __shfl_xor(sq[r], 8, 64);
  }
  float mu[4], rs[4];
#pragma unroll
  for (int r = 0; r < 4; ++r) {
    mu[r] = sm[r] * (1.f / 256.f);
    float var = sq[r] * (1.f / 256.f) - mu[r] * mu[r];
    rs[r] = rsqrtf(var + 1e-5f);
  }
#pragma unroll
  for (int c = 0; c < 16; ++c) {
    int col = c * 16 + s;
    float gg = lg[col], bb = lb[col];
#pragma unroll
    for (int r = 0; r < 4; ++r) {
      int row = n0 + wrow + g * 4 + r;
      if (row < NN) {
        float o = fmaxf(0.f, (zac[c][r] - mu[r]) * rs[r] * gg + bb);
        h_bf[(size_t)row * EMB + col] = f2bf(o);
      }
    }
  }
}

// ---------------- pooling / output ----------------

__global__ void k_pool(const u16* __restrict__ h_bf, const int* __restrict__ batch,
                       float* __restrict__ pooled) {
  int t = threadIdx.x; // col
  int n0 = blockIdx.x * 64;
  if (n0 >= NN) return;
  int nend = n0 + 64;
  if (nend > NN) nend = NN;
  float run = 0.f;
  int cur = batch[n0];
  for (int n = n0; n < nend; ++n) {
    int b = batch[n];
    if (b != cur) {
      atomicAdd(&pooled[(size_t)cur * EMB + t], run);
      run = 0.f;
      cur = b;
    }
    run += bf2f(h_bf[(size_t)n * EMB + t]);
  }
  atomicAdd(&pooled[(size_t)cur * EMB + t], run);
}

__global__ void k_out(const float* __restrict__ pooled, const float* __restrict__ gcnt,
                      const float* __restrict__ ow, const float* __restrict__ ob,
                      float* __restrict__ out) {
  __shared__ float prow[EMB];
  int g = blockIdx.x, t = threadIdx.x;
  float rc = 1.f / fmaxf(gcnt[g], 1.f);
  for (int i = t; i < EMB; i += TASKS) prow[i] = pooled[(size_t)g * EMB + i] * rc;
  __syncthreads();
  float acc = ob[t];
#pragma unroll 4
  for (int d = 0; d < EMB; ++d) acc += prow[d] * ow[d * TASKS + t];
  out[(size_t)g * TASKS + t] = acc;
}

// ---------------- launch ----------------

extern "C" void kernel_launch(void* const* d_in, const int* in_sizes, int n_in,
                              void* d_out, int out_size, void* d_ws, size_t ws_size,
                              hipStream_t stream) {
  const int* x = (const int*)d_in[0];
  const int* eidx = (const int*)d_in[1];
  const int* eattr = (const int*)d_in[2];
  const int* batch = (const int*)d_in[3];
  const float* aemb = (const float*)d_in[4];
  const float* bemb = (const float*)d_in[5];
  const float* wq = (const float*)d_in[6];
  const float* bq = (const float*)d_in[7];
  const float* wk = (const float*)d_in[8];
  const float* bk = (const float*)d_in[9];
  const float* fcw = (const float*)d_in[10];
  const float* fcb = (const float*)d_in[11];
  const float* lg = (const float*)d_in[12];
  const float* lb = (const float*)d_in[13];
  const float* ow = (const float*)d_in[14];
  const float* ob = (const float*)d_in[15];
  float* out = (float*)d_out;

  size_t off = 0;
  auto alloc = [&](size_t bytes) -> void* {
    void* r = (char*)d_ws + off;
    off += (bytes + 255) & ~(size_t)255;
    return r;
  };
  u16* h_bf = (u16*)alloc((size_t)NN * EMB * 2);        // 25.6 MB
  u16* region = (u16*)alloc((size_t)HE * NS * 2);       // 102.5 MB (knF | msg,s1,s2,s3)
  u16* knF = region;
  u16* msg = region;
  u16* s1 = region + (size_t)NN * EMB;
  u16* s2 = region + (size_t)2 * NN * EMB;
  u16* s3 = region + (size_t)3 * NN * EMB;
  u16* hF = (u16*)alloc((size_t)EMB * NS * 2);          // 25.6 MB
  float* kvs = (float*)alloc((size_t)HE * EMB * 4);     // 1 MB
  float* Mm = (float*)alloc((size_t)HE * EMB * 4);      // 1 MB
  u16* MTF = (u16*)alloc((size_t)HE * EMB * 2);         // 0.5 MB
  u16* wqF = (u16*)alloc((size_t)NL * HE * EMB * 2);    // 2.1 MB
  u16* wkF = (u16*)alloc((size_t)NL * HE * EMB * 2);    // 2.1 MB
  u16* fcwF = (u16*)alloc((size_t)NL * 2048 * EMB * 2); // 4.2 MB
  float* cvec = (float*)alloc((size_t)NH * EMB * 4);
  float* ksh = (float*)alloc((size_t)(HE + EMB) * 4); // ks_sum | h_sum
  float* ks_sum = ksh;
  float* h_sum = ksh + HE;
  float* dinv_i = (float*)alloc((size_t)NN * 4);
  float* dinv_j = (float*)alloc((size_t)NN * 4);
  int* deg_i = (int*)alloc((size_t)NN * 4);
  int* deg_j = (int*)alloc((size_t)NN * 4);
  int* offs = (int*)alloc((size_t)(NN + 1) * 4);
  int* cursor = (int*)alloc((size_t)NN * 4);
  int* csr_col = (int*)alloc((size_t)NE * 4);
  float* csr_adj = (float*)alloc((size_t)NE * 4);
  int* csr_pack = (int*)alloc((size_t)NE * 4);
  float* pooled = (float*)alloc((size_t)NG * EMB * 4);
  float* gcnt = (float*)alloc((size_t)NG * 4);

  if (off > ws_size) {
    k_fill<<<(out_size + 255) / 256, 256, 0, stream>>>(out, out_size, 1048576.f);
    return;
  }

  const int* row = eidx;
  const int* colp = eidx + NE;

  k_zero<<<(NN + 255) / 256, 256, 0, stream>>>((u32*)deg_i, NN);
  k_zero<<<(NN + 255) / 256, 256, 0, stream>>>((u32*)deg_j, NN);
  k_zero<<<(NN + 255) / 256, 256, 0, stream>>>((u32*)cursor, NN);
  k_zero<<<(NG + 255) / 256, 256, 0, stream>>>((u32*)gcnt, NG);
  k_zero<<<(NG * EMB + 255) / 256, 256, 0, stream>>>((u32*)pooled, NG * EMB);

  // one-time fragment-major weight packs
  k_frag<<<dim3(8, 64, NL), 64, 0, stream>>>(wq, wqF, 1024, 64, 0,
                                             (long)EMB * HE, (long)HE * EMB);
  k_frag<<<dim3(8, 64, NL), 64, 0, stream>>>(wk, wkF, 1024, 64, 0,
                                             (long)EMB * HE, (long)HE * EMB);
  k_frag<<<dim3(64, 16, NL), 64, 0, stream>>>(fcw, fcwF, 256, 16, 0,
                                              (long)2048 * EMB, (long)2048 * EMB);

  k_atom<<<NN, EMB, 0, stream>>>(x, aemb, h_bf);
  k_deg<<<NE / 256, 256, 0, stream>>>(row, colp, deg_i, deg_j);
  k_dinv<<<(NN + 255) / 256, 256, 0, stream>>>(deg_i, deg_j, dinv_i, dinv_j);
  k_scan<<<1, 1024, 0, stream>>>(deg_i, offs);
  k_csr<<<NE / 256, 256, 0, stream>>>(row, colp, eattr, dinv_i, dinv_j, offs, cursor,
                                      csr_col, csr_adj, csr_pack);
  k_gcnt<<<(NN + 255) / 256, 256, 0, stream>>>(batch, gcnt);

  for (int l = 0; l < NL; ++l) {
    const float* fcw_l = fcw + (size_t)l * 2048 * EMB;
    k_zero<<<(HE + EMB + 255) / 256, 256, 0, stream>>>((u32*)ksh, HE + EMB);
    k_zero<<<(HE * EMB + 255) / 256, 256, 0, stream>>>((u32*)kvs, HE * EMB);
    // --- phase 1: region holds knF ---
    k_projk<<<dim3(GB64, NH), 256, 0, stream>>>(h_bf, wkF + (size_t)l * HE * EMB,
                                                bk + (size_t)l * HE, knF, ks_sum, h_sum);
    k_htrf<<<dim3(GB64, 4), 256, 0, stream>>>(h_bf, hF);
    k_kvs<<<dim3(8, KVS_SL), 256, 0, stream>>>(knF, hF, kvs);
    k_mpre<<<HE, 256, 0, stream>>>(kvs, fcw_l, Mm);
    k_frag<<<dim3(8, 16, NH), 64, 0, stream>>>(Mm, MTF, 256, 64, 16,
                                               (long)EMB * EMB, 0);
    k_cvec<<<NH, 256, 0, stream>>>(h_sum, fcw_l, cvec);
    // --- phase 2: knF dead; region becomes msg/s1/s2/s3 ---
    k_message<<<NN / 16, 256, 0, stream>>>(bemb + (size_t)l * 3 * 10 * EMB, offs, csr_adj,
                                           csr_pack, msg);
    k_spmm<<<NN / 4, 256, 0, stream>>>(h_bf, msg, offs, csr_col, csr_adj, s1);
    k_spmm<<<NN / 4, 256, 0, stream>>>(s1, msg, offs, csr_col, csr_adj, s2);
    k_spmm<<<NN / 4, 256, 0, stream>>>(s2, msg, offs, csr_col, csr_adj, s3);
    k_fused<<<GB128, 512, 0, stream>>>(h_bf, s1, s2, s3, wqF + (size_t)l * HE * EMB,
                                       bq + (size_t)l * HE, MTF, cvec, ks_sum,
                                       fcwF + (size_t)l * 2048 * EMB, fcb + (size_t)l * EMB,
                                       lg + (size_t)l * EMB, lb + (size_t)l * EMB);
  }
  k_pool<<<(NN + 63) / 64, 256, 0, stream>>>(h_bf, batch, pooled);
  k_out<<<NG, TASKS, 0, stream>>>(pooled, gcnt, ow, ob, out);
}